// Round 1
// 2912.663 us; speedup vs baseline: 3.2464x; 3.2464x over previous
//
#include <hip/hip_runtime.h>
#include <hip/hip_bf16.h>

typedef __hip_bfloat16 bf16;
typedef __attribute__((ext_vector_type(8))) __bf16 bf16x8;
typedef __attribute__((ext_vector_type(4))) float f32x4;

#define NB   16
#define HIN  32
#define WIN_ 32
#define C    512
#define HO   64
#define WO   64

__device__ __forceinline__ float lrelu(float v) { return v > 0.f ? v : 0.2f * v; }
__device__ __forceinline__ unsigned short f2bu(float f) {
    union { __hip_bfloat16 h; unsigned short u; } cv;
    cv.h = __float2bfloat16(f);
    return cv.u;
}

// s[b,co] = sum_ci w[b,ci]*fw[ci,co]*scale + fb[co]
__global__ __launch_bounds__(256) void style_fc_kernel(
    const float* __restrict__ w, const float* __restrict__ fw,
    const float* __restrict__ fb, float* __restrict__ s)
{
    int b = blockIdx.x;
    __shared__ float wrow[C];
    for (int i = threadIdx.x; i < C; i += 256) wrow[i] = w[b * C + i];
    __syncthreads();
    const float scale = 0.044194173824159216f;  // 1/sqrt(512)
    for (int co = threadIdx.x; co < C; co += 256) {
        float acc = 0.f;
        for (int ci = 0; ci < C; ci++)
            acc = fmaf(wrow[ci], fw[ci * C + co], acc);
        s[b * C + co] = acc * scale + fb[co];
    }
}

// preQ[ci][co] = sum_t w[t][ci][co]^2  (batch-independent; one pass over weights)
__global__ __launch_bounds__(256) void presq_kernel(
    const float* __restrict__ cw, float* __restrict__ q)
{
    const int ci = blockIdx.x;
    for (int co = threadIdx.x; co < C; co += 256) {
        float a = 0.f;
        #pragma unroll
        for (int t = 0; t < 9; ++t) {
            float v = cw[((size_t)t * C + ci) * C + co];
            a = fmaf(v, v, a);
        }
        q[ci * C + co] = a;
    }
}

// g[b,co] = wscale * rsqrt(wscale^2 * sum_ci preQ[ci][co]*s^2[b][ci] + 1e-8)
__global__ __launch_bounds__(256) void demod2_kernel(
    const float* __restrict__ s, const float* __restrict__ q,
    float* __restrict__ g, float wscale)
{
    const int b = blockIdx.y;
    const int co = blockIdx.x * 256 + threadIdx.x;
    __shared__ float s2[C];
    for (int i = threadIdx.x; i < C; i += 256) {
        float v = s[b * C + i];
        s2[i] = v * v;
    }
    __syncthreads();
    float acc = 0.f;
    for (int ci = 0; ci < C; ++ci)
        acc = fmaf(q[ci * C + co], s2[ci], acc);
    g[b * C + co] = wscale / sqrtf(acc * wscale * wscale + 1e-8f);
}

// Implicit-GEMM MFMA conv. MODE 1: transposed 3x3 stride-2 SAME conv (fp32 in,
// fp32 t0 out, epilogue *g). MODE 2: 3x3 stride-1 SAME conv (bf16 in, epilogue
// *g + noise + bias + lrelu, fp32 out).
// Tile: M=128 (2 output rows x 64 px), N=128 cout, BK=32. 4 waves in 2x2; each
// wave owns 64x64 via 4x4 fragments of mfma_f32_16x16x32_bf16.
// LDS tiles stored [row][32 k] as packed 64B rows: fragment ds_read_b128 at
// row=(lane&15)+16*frag, slot=lane>>4 sweeps a contiguous 1KB block ->
// conflict-free. Staging writes are linear in tid -> conflict-free.
// Style s is folded into B during staging (bf16(w*s)); demod g in epilogue.
template<int MODE>
__global__ __launch_bounds__(256) void conv_mfma(
    const void* __restrict__ xin, const float* __restrict__ cw,
    const float* __restrict__ sstyle, const float* __restrict__ g,
    const float* __restrict__ noise, const float* __restrict__ sn,
    const float* __restrict__ bias, float* __restrict__ out)
{
    const int n0  = blockIdx.x * 128;
    const int oyb = blockIdx.y;          // output row pair index
    const int b   = blockIdx.z;
    const int tid  = threadIdx.x;
    const int lane = tid & 63;
    const int wave = tid >> 6;
    const int wr = wave >> 1, wc = wave & 1;
    const int ln15 = lane & 15, lg = lane >> 4;

    __shared__ unsigned short As[128 * 32];
    __shared__ unsigned short Bs[128 * 32];
    __shared__ float srow[C];
    __shared__ float nzs[128];

    for (int i = tid; i < C; i += 256) srow[i] = sstyle[b * C + i];
    if constexpr (MODE == 2) {
        if (tid < 128) {
            int h = tid >> 6, ox = tid & 63;
            nzs[tid] = noise[(b * HO + oyb * 2 + h) * WO + ox];
        }
    }
    __syncthreads();

    const float* xf = (const float*)xin;
    const unsigned short* xb = (const unsigned short*)xin;

    f32x4 acc[4][4];
    #pragma unroll
    for (int i = 0; i < 4; ++i)
        #pragma unroll
        for (int j = 0; j < 4; ++j) {
            f32x4 z = {0.f, 0.f, 0.f, 0.f};
            acc[i][j] = z;
        }

    for (int t = 0; t < 9; ++t) {
        const int ky = t / 3, kx = t % 3;   // (dy,dx) for MODE 2
        if (MODE == 1 && oyb == 0 && ky == 0) continue;  // whole tap invalid
        const float* wt = cw + (size_t)t * C * C;

        for (int c0 = 0; c0 < C; c0 += 32) {
            // ---- stage A: [128 m][32 k] bf16 (write 16B at byte 16*s, linear) ----
            #pragma unroll
            for (int i2 = 0; i2 < 2; ++i2) {
                int s = tid + 256 * i2;
                int m = s >> 2, q = s & 3;
                int h = m >> 6, ox = m & 63;
                int4 v{0, 0, 0, 0};
                if constexpr (MODE == 2) {
                    int iy = oyb * 2 + h + ky - 1;
                    int ix = ox + kx - 1;
                    if ((unsigned)iy < (unsigned)HO && (unsigned)ix < (unsigned)WO)
                        v = *(const int4*)&xb[((size_t)((b * HO + iy) * WO + ix) << 9) + c0 + q * 8];
                } else {
                    // row half h active iff (oy+ky) even; iy=(oy+ky-2)/2, ix=(ox+kx-2)/2
                    if (((h + ky) & 1) == 0) {
                        int iy = oyb + ((h + ky - 2) >> 1);
                        int u = ox + kx - 2;
                        if ((u & 1) == 0 && u >= 0 && (unsigned)iy < (unsigned)HIN) {
                            int ix = u >> 1;
                            const float* xp = &xf[((size_t)((b * HIN + iy) * WIN_ + ix) << 9) + c0 + q * 8];
                            float4 f0 = *(const float4*)xp;
                            float4 f1 = *(const float4*)(xp + 4);
                            v.x = (int)f2bu(f0.x) | ((int)f2bu(f0.y) << 16);
                            v.y = (int)f2bu(f0.z) | ((int)f2bu(f0.w) << 16);
                            v.z = (int)f2bu(f1.x) | ((int)f2bu(f1.y) << 16);
                            v.w = (int)f2bu(f1.z) | ((int)f2bu(f1.w) << 16);
                        }
                    }
                }
                *(int4*)&As[s * 8] = v;
            }
            // ---- stage B: transpose w[k][n] -> Bs[n][32 k], fold s (8B at 8*s, linear) ----
            #pragma unroll
            for (int it = 0; it < 4; ++it) {
                int s = tid + 256 * it;
                int n = s >> 3, kq = s & 7;
                int k = c0 + kq * 4;
                float4 sv = *(const float4*)&srow[k];
                const float* wp = wt + (size_t)k * C + n0 + n;
                unsigned short u0 = f2bu(wp[0]     * sv.x);
                unsigned short u1 = f2bu(wp[C]     * sv.y);
                unsigned short u2 = f2bu(wp[2 * C] * sv.z);
                unsigned short u3 = f2bu(wp[3 * C] * sv.w);
                int2 pk;
                pk.x = (int)u0 | ((int)u1 << 16);
                pk.y = (int)u2 | ((int)u3 << 16);
                *(int2*)&Bs[s * 4] = pk;
            }
            __syncthreads();
            // ---- fragments + MFMA ----
            bf16x8 aF[4], bF[4];
            #pragma unroll
            for (int mi = 0; mi < 4; ++mi)
                aF[mi] = *(const bf16x8*)&As[(wr * 64 + mi * 16 + ln15) * 32 + lg * 8];
            #pragma unroll
            for (int ni = 0; ni < 4; ++ni)
                bF[ni] = *(const bf16x8*)&Bs[(wc * 64 + ni * 16 + ln15) * 32 + lg * 8];
            #pragma unroll
            for (int mi = 0; mi < 4; ++mi)
                #pragma unroll
                for (int ni = 0; ni < 4; ++ni)
                    acc[mi][ni] = __builtin_amdgcn_mfma_f32_16x16x32_bf16(
                        aF[mi], bF[ni], acc[mi][ni], 0, 0, 0);
            __syncthreads();
        }
    }

    // ---- epilogue: D col = lane&15 (n), row = (lane>>4)*4 + reg (m) ----
    #pragma unroll
    for (int ni = 0; ni < 4; ++ni) {
        int n = n0 + wc * 64 + ni * 16 + ln15;
        float gv = g[b * C + n];
        float snv = 0.f, bv = 0.f;
        if constexpr (MODE == 2) { snv = sn[n]; bv = bias[n]; }
        #pragma unroll
        for (int mi = 0; mi < 4; ++mi) {
            #pragma unroll
            for (int j = 0; j < 4; ++j) {
                int m = wr * 64 + mi * 16 + lg * 4 + j;
                int h = m >> 6, ox = m & 63;
                int oy = oyb * 2 + h;
                size_t idx = ((size_t)((b * HO + oy) * WO + ox) << 9) + n;
                float v = acc[mi][ni][j] * gv;
                if constexpr (MODE == 2) v = lrelu(v + snv * nzs[m] + bv);
                out[idx] = v;
            }
        }
    }
}

// 4x4 FIR blur ([1,3,3,1] outer /16, pads lo=1 hi=2) + noise + bias + lrelu -> x1 (bf16)
__global__ __launch_bounds__(128) void blur_kernel(
    const float* __restrict__ t0, const float* __restrict__ noise1,
    const float* __restrict__ sn1, const float* __restrict__ bias1,
    unsigned short* __restrict__ x1)
{
    const int ox = blockIdx.x, oy = blockIdx.y, b = blockIdx.z;
    const float nz = noise1[(b * HO + oy) * WO + ox];
    const int c = threadIdx.x * 4;
    float a0 = 0.f, a1 = 0.f, a2 = 0.f, a3 = 0.f;
    const float F[4] = {1.f, 3.f, 3.f, 1.f};
    #pragma unroll
    for (int i = 0; i < 4; ++i) {
        int iy = oy + i - 1;
        if ((unsigned)iy >= (unsigned)HO) continue;
        #pragma unroll
        for (int j = 0; j < 4; ++j) {
            int ix = ox + j - 1;
            if ((unsigned)ix >= (unsigned)WO) continue;
            float wgt = F[i] * F[j];
            const float4 v = *(const float4*)&t0[((size_t)((b * HO + iy) * WO + ix) << 9) + c];
            a0 = fmaf(wgt, v.x, a0); a1 = fmaf(wgt, v.y, a1);
            a2 = fmaf(wgt, v.z, a2); a3 = fmaf(wgt, v.w, a3);
        }
    }
    const float4 sv = *(const float4*)&sn1[c];
    const float4 bv = *(const float4*)&bias1[c];
    a0 = lrelu(fmaf(sv.x, nz, a0 * 0.0625f) + bv.x);
    a1 = lrelu(fmaf(sv.y, nz, a1 * 0.0625f) + bv.y);
    a2 = lrelu(fmaf(sv.z, nz, a2 * 0.0625f) + bv.z);
    a3 = lrelu(fmaf(sv.w, nz, a3 * 0.0625f) + bv.w);
    int2 pk;
    pk.x = (int)f2bu(a0) | ((int)f2bu(a1) << 16);
    pk.y = (int)f2bu(a2) | ((int)f2bu(a3) << 16);
    *(int2*)&x1[((size_t)((b * HO + oy) * WO + ox) << 9) + c] = pk;
}

// 1x1 conv (no demod) + bias + lrelu -> rgb (fp32). Recomputes its own style vector
// so it never reads the d_out-tail scratch it overwrites.
__global__ __launch_bounds__(256) void torgb_kernel(
    const float* __restrict__ x2, const float* __restrict__ w,
    const float* __restrict__ fw, const float* __restrict__ fb,
    const float* __restrict__ wr, const float* __restrict__ biasr,
    float* __restrict__ rgb)
{
    const int b = blockIdx.y;
    const int oy = blockIdx.x * 4 + (threadIdx.x >> 6);
    const int ox = threadIdx.x & 63;
    __shared__ float wrow[C];
    __shared__ float weff[C][3];
    for (int i = threadIdx.x; i < C; i += 256) wrow[i] = w[b * C + i];
    __syncthreads();
    const float scale = 0.044194173824159216f;  // 1/sqrt(512), fc scale AND 1x1 conv wscale
    for (int ci = threadIdx.x; ci < C; ci += 256) {
        float acc = 0.f;
        for (int k = 0; k < C; k++)
            acc = fmaf(wrow[k], fw[k * C + ci], acc);
        float s = acc * scale + fb[ci];
        float sc = scale * s;
        weff[ci][0] = sc * wr[ci * 3 + 0];
        weff[ci][1] = sc * wr[ci * 3 + 1];
        weff[ci][2] = sc * wr[ci * 3 + 2];
    }
    __syncthreads();
    const float* px = x2 + ((size_t)(b * HO + oy) * WO + ox) * C;
    float a0 = 0.f, a1 = 0.f, a2 = 0.f;
    for (int ci = 0; ci < C; ci++) {
        float f = px[ci];
        a0 = fmaf(f, weff[ci][0], a0);
        a1 = fmaf(f, weff[ci][1], a1);
        a2 = fmaf(f, weff[ci][2], a2);
    }
    float* dst = rgb + ((size_t)(b * HO + oy) * WO + ox) * 3;
    dst[0] = lrelu(a0 + biasr[0]);
    dst[1] = lrelu(a1 + biasr[1]);
    dst[2] = lrelu(a2 + biasr[2]);
}

extern "C" void kernel_launch(void* const* d_in, const int* in_sizes, int n_in,
                              void* d_out, int out_size, void* d_ws, size_t ws_size,
                              hipStream_t stream)
{
    (void)in_sizes; (void)n_in; (void)out_size; (void)ws_size;
    const float* x       = (const float*)d_in[0];
    const float* w       = (const float*)d_in[1];
    const float* noise1  = (const float*)d_in[2];
    const float* noise2  = (const float*)d_in[3];
    const float* fcl1_w  = (const float*)d_in[4];
    const float* fcl1_b  = (const float*)d_in[5];
    const float* conv1_w = (const float*)d_in[6];
    const float* sn1     = (const float*)d_in[7];
    const float* bias1   = (const float*)d_in[8];
    const float* fcl2_w  = (const float*)d_in[9];
    const float* fcl2_b  = (const float*)d_in[10];
    const float* conv2_w = (const float*)d_in[11];
    const float* sn2     = (const float*)d_in[12];
    const float* bias2   = (const float*)d_in[13];
    const float* fclr_w  = (const float*)d_in[14];
    const float* fclr_b  = (const float*)d_in[15];
    const float* convr_w = (const float*)d_in[16];
    const float* biasr   = (const float*)d_in[17];

    float* out_x2  = (float*)d_out;               // 16*64*64*512 fp32 = 128 MiB
    float* out_rgb = out_x2 + 33554432;           // 16*64*64*3 fp32 = 768 KiB

    // Small scratch in the rgb tail of d_out (dead until torgb; torgb only WRITES
    // there and recomputes its style itself): 4 * 32 KiB = 128 KiB <= 768 KiB.
    float* s1 = out_rgb;
    float* s2 = out_rgb + 8192;
    float* g1 = out_rgb + 16384;
    float* g2 = out_rgb + 24576;

    // preQ scratch (1 MiB each) lives in the out_x2/t0 region, which is dead
    // until conv1 writes t0 (all preQ/demod consumers run before conv1).
    float* q1 = out_x2;
    float* q2 = out_x2 + 262144;

    // d_ws usage: exactly 64 MiB — bf16 x1 only.
    unsigned short* x1 = (unsigned short*)d_ws;   // 33554432 bf16 = 67108864 B

    float* t0 = out_x2;  // pre-blur conv1 output (fp32), overwritten by x2 later

    const float WS33 = 0.014731391274719739f;     // 1/sqrt(9*512)

    style_fc_kernel<<<NB, 256, 0, stream>>>(w, fcl1_w, fcl1_b, s1);
    style_fc_kernel<<<NB, 256, 0, stream>>>(w, fcl2_w, fcl2_b, s2);
    presq_kernel<<<C, 256, 0, stream>>>(conv1_w, q1);
    presq_kernel<<<C, 256, 0, stream>>>(conv2_w, q2);
    demod2_kernel<<<dim3(2, NB), 256, 0, stream>>>(s1, q1, g1, WS33);
    demod2_kernel<<<dim3(2, NB), 256, 0, stream>>>(s2, q2, g2, WS33);
    conv_mfma<1><<<dim3(4, 32, NB), 256, 0, stream>>>(
        (const void*)x, conv1_w, s1, g1, nullptr, nullptr, nullptr, t0);
    blur_kernel<<<dim3(WO, HO, NB), 128, 0, stream>>>(t0, noise1, sn1, bias1, x1);
    conv_mfma<2><<<dim3(4, 32, NB), 256, 0, stream>>>(
        (const void*)x1, conv2_w, s2, g2, noise2, sn2, bias2, out_x2);
    torgb_kernel<<<dim3(16, NB), 256, 0, stream>>>(out_x2, w, fclr_w, fclr_b, convr_w, biasr, out_rgb);
}

// Round 2
// 1153.412 us; speedup vs baseline: 8.1979x; 2.5253x over previous
//
#include <hip/hip_runtime.h>
#include <hip/hip_bf16.h>

typedef __hip_bfloat16 bf16;
typedef __attribute__((ext_vector_type(8))) __bf16 bf16x8;
typedef __attribute__((ext_vector_type(4))) float f32x4;
typedef unsigned short ushort_t;

#define NB   16
#define HIN  32
#define WIN_ 32
#define C    512
#define HO   64
#define WO   64

__device__ __forceinline__ float lrelu(float v) { return v > 0.f ? v : 0.2f * v; }
__device__ __forceinline__ unsigned short f2bu(float f) {
    union { __hip_bfloat16 h; unsigned short u; } cv;
    cv.h = __float2bfloat16(f);
    return cv.u;
}
// async global->LDS, 16B per lane; lds base must be wave-uniform (lane writes +lane*16B)
__device__ __forceinline__ void gload16(const ushort_t* g, ushort_t* l) {
    __builtin_amdgcn_global_load_lds(
        (const __attribute__((address_space(1))) void*)g,
        (__attribute__((address_space(3))) void*)l, 16, 0, 0);
}

// s[b,co] = sum_ci w[b,ci]*fw[ci,co]*scale + fb[co]
__global__ __launch_bounds__(256) void style_fc_kernel(
    const float* __restrict__ w, const float* __restrict__ fw,
    const float* __restrict__ fb, float* __restrict__ s)
{
    int b = blockIdx.x;
    __shared__ float wrow[C];
    for (int i = threadIdx.x; i < C; i += 256) wrow[i] = w[b * C + i];
    __syncthreads();
    const float scale = 0.044194173824159216f;  // 1/sqrt(512)
    for (int co = threadIdx.x; co < C; co += 256) {
        float acc = 0.f;
        for (int ci = 0; ci < C; ci++)
            acc = fmaf(wrow[ci], fw[ci * C + co], acc);
        s[b * C + co] = acc * scale + fb[co];
    }
}

// One pass over a weight tensor: emit (a) bf16 transposed layout
// wb[t][ct][n=co][kk=ci&31] ready for global_load_lds staging, (b) q[ci][co]=sum_t w^2.
__global__ __launch_bounds__(256) void wprep_kernel(
    const float* __restrict__ cw, ushort_t* __restrict__ wb,
    float* __restrict__ q)
{
    const int nc = blockIdx.x;   // co block of 64
    const int ct = blockIdx.y;   // ci block of 32
    const int tid = threadIdx.x;
    __shared__ float tile[32][65];
    float qacc[8];
    #pragma unroll
    for (int p = 0; p < 8; ++p) qacc[p] = 0.f;
    const int rr = tid >> 6;        // 0..3 (read row within pass)
    const int cc = tid & 63;        // 0..63 (read col)
    const int n  = tid >> 2;        // 0..63 (write col)
    const int kq = tid & 3;         // write kk quad -> kk = kq*8..+7
    for (int t = 0; t < 9; ++t) {
        #pragma unroll
        for (int p = 0; p < 8; ++p) {
            const int r = p * 4 + rr;
            float v = cw[((size_t)(t * C + ct * 32 + r)) * C + nc * 64 + cc];
            tile[r][cc] = v;
            qacc[p] = fmaf(v, v, qacc[p]);
        }
        __syncthreads();
        unsigned int d[4];
        #pragma unroll
        for (int j2 = 0; j2 < 4; ++j2)
            d[j2] = (unsigned int)f2bu(tile[kq * 8 + 2 * j2][n])
                  | ((unsigned int)f2bu(tile[kq * 8 + 2 * j2 + 1][n]) << 16);
        int4 w4 = { (int)d[0], (int)d[1], (int)d[2], (int)d[3] };
        *(int4*)&wb[(((size_t)t * 16 + ct) * 512 + nc * 64 + n) * 32 + kq * 8] = w4;
        __syncthreads();
    }
    #pragma unroll
    for (int p = 0; p < 8; ++p)
        q[(ct * 32 + p * 4 + rr) * C + nc * 64 + cc] = qacc[p];
}

// g[b,co] = wscale * rsqrt(wscale^2 * sum_ci q[ci][co]*s^2[b][ci] + 1e-8)
__global__ __launch_bounds__(256) void demod2_kernel(
    const float* __restrict__ s, const float* __restrict__ q,
    float* __restrict__ g, float wscale)
{
    const int b = blockIdx.y;
    const int co = blockIdx.x * 256 + threadIdx.x;
    __shared__ float s2[C];
    for (int i = threadIdx.x; i < C; i += 256) {
        float v = s[b * C + i];
        s2[i] = v * v;
    }
    __syncthreads();
    float acc = 0.f;
    for (int ci = 0; ci < C; ++ci)
        acc = fmaf(q[ci * C + co], s2[ci], acc);
    g[b * C + co] = wscale / sqrtf(acc * wscale * wscale + 1e-8f);
}

// x*s1 -> bf16, padded [16][33][33][512] with zero halo at iy=0 / ix=0
__global__ __launch_bounds__(128) void xprep_kernel(
    const float* __restrict__ x, const float* __restrict__ s1,
    ushort_t* __restrict__ xp)
{
    const int ix = blockIdx.x;   // 0..32
    const int iy = blockIdx.y;   // 0..32
    const int b  = blockIdx.z;
    const int c  = threadIdx.x * 4;
    int2 pk{0, 0};
    if (iy > 0 && ix > 0) {
        const float4 xv = *(const float4*)&x[(((size_t)b * HIN + iy - 1) * WIN_ + ix - 1) * C + c];
        const float4 sv = *(const float4*)&s1[b * C + c];
        pk.x = (int)f2bu(xv.x * sv.x) | ((int)f2bu(xv.y * sv.y) << 16);
        pk.y = (int)f2bu(xv.z * sv.z) | ((int)f2bu(xv.w * sv.w) << 16);
    }
    *(int2*)&xp[(((size_t)b * 33 + iy) * 33 + ix) * 512 + c] = pk;
}

__global__ __launch_bounds__(256) void zero_kernel(int4* __restrict__ p, int n16)
{
    int i = blockIdx.x * 256 + threadIdx.x;
    int4 z{0, 0, 0, 0};
    if (i < n16) p[i] = z;
}

// Implicit-GEMM MFMA conv, 2-phase double-buffered, all staging via global_load_lds.
// MODE 1: transposed 3x3 s2 conv restructured into parity classes (grid.y = class*8+iblock);
//   input = prepped bf16 x*s1 with halo [16][33][33][512]; out = t0 fp32, epilogue *g.
// MODE 2: 3x3 s1 conv; input = haloed bf16 x1*s2 [8][66][66][512]; epilogue *g+noise+bias+lrelu.
// Tile M=128 x N=128 x BK=32; 4 waves 2x2; per wave 4x4 frags of mfma_f32_16x16x32_bf16.
// LDS tiles [row][32k] packed 64B rows: frag ds_read_b128 2-way-conflict (free); staging linear.
template<int MODE>
__global__ __launch_bounds__(256) void conv_mfma(
    const ushort_t* __restrict__ xin, const ushort_t* __restrict__ wb,
    const float* __restrict__ g,
    const float* __restrict__ noise, const float* __restrict__ sn,
    const float* __restrict__ bias, float* __restrict__ out, int b0)
{
    const int n0 = blockIdx.x * 128;
    const int gy = blockIdx.y;
    const int bz = blockIdx.z;
    const int b  = b0 + bz;
    const int tid = threadIdx.x;
    const int lane = tid & 63, wave = tid >> 6;
    const int wr = wave >> 1, wc = wave & 1;
    const int ln15 = lane & 15, lg = lane >> 4;

    __shared__ ushort_t As[2][4096];
    __shared__ ushort_t Bs[2][4096];
    __shared__ float nzs[128];

    int ntap = 9;
    int tapt[4] = {0, 0, 0, 0};
    int tapoff[4] = {0, 0, 0, 0};
    int i0 = 0, cla = 0, clc = 0, oyb = 0;
    if constexpr (MODE == 1) {
        const int cl = gy >> 3;
        i0 = (gy & 7) * 4;
        cla = cl >> 1; clc = cl & 1;
        int kys[2], kxs[2], nky, nkx;
        if (cla == 0) { kys[0] = 0; kys[1] = 2; nky = 2; } else { kys[0] = 1; nky = 1; }
        if (clc == 0) { kxs[0] = 0; kxs[1] = 2; nkx = 2; } else { kxs[0] = 1; nkx = 1; }
        ntap = 0;
        for (int u = 0; u < nky; ++u)
            for (int v = 0; v < nkx; ++v) {
                int ky = kys[u], kx = kxs[v];
                tapt[ntap] = ky * 3 + kx;
                int dy = (cla + ky - 2) >> 1, dx = (clc + kx - 2) >> 1;
                tapoff[ntap] = (dy * 33 + dx) * 512;
                ntap++;
            }
    } else {
        oyb = gy;
        if (tid < 128)
            nzs[tid] = noise[(b * HO + oyb * 2 + (tid >> 6)) * WO + (tid & 63)];
    }

    // per-thread global bases (element units) for the two 16B stage issues
    int abase[2], bbase[2];
    #pragma unroll
    for (int i2 = 0; i2 < 2; ++i2) {
        const int s = tid + 256 * i2;
        const int q = s & 3, m = s >> 2;
        if constexpr (MODE == 2) {
            abase[i2] = ((bz * 66 + oyb * 2 + (m >> 6)) * 66 + (m & 63)) * 512 + q * 8;
        } else {
            abase[i2] = ((b * 33 + i0 + (m >> 5) + 1) * 33 + (m & 31) + 1) * 512 + q * 8;
        }
        bbase[i2] = n0 * 32 + s * 8;
    }
    const int ldso[2] = { wave * 512, wave * 512 + 2048 };

    auto stage = [&](int it, int bufi) {
        const int tp = it >> 4, ci = it & 15, c0 = ci << 5;
        int t, aoff;
        if constexpr (MODE == 1) { t = tapt[tp]; aoff = tapoff[tp] + c0; }
        else { const int ky = tp / 3, kx = tp - ky * 3; t = tp; aoff = (ky * 66 + kx) * 512 + c0; }
        const int boff = (t * 16 + ci) * 16384;
        #pragma unroll
        for (int i2 = 0; i2 < 2; ++i2) {
            gload16(xin + abase[i2] + aoff, &As[bufi][ldso[i2]]);
            gload16(wb + boff + bbase[i2], &Bs[bufi][ldso[i2]]);
        }
    };

    f32x4 acc[4][4];
    #pragma unroll
    for (int i = 0; i < 4; ++i)
        #pragma unroll
        for (int j = 0; j < 4; ++j) {
            f32x4 z = {0.f, 0.f, 0.f, 0.f};
            acc[i][j] = z;
        }

    const int nstep = ntap * 16;
    stage(0, 0);
    __syncthreads();   // drains vmcnt(0): buf0 ready (and nzs visible)

    for (int it = 0; it < nstep; ++it) {
        const int cur = it & 1;
        if (it + 1 < nstep) stage(it + 1, cur ^ 1);
        bf16x8 aF[4], bF[4];
        #pragma unroll
        for (int mi = 0; mi < 4; ++mi)
            aF[mi] = *(const bf16x8*)&As[cur][(wr * 64 + mi * 16 + ln15) * 32 + lg * 8];
        #pragma unroll
        for (int ni = 0; ni < 4; ++ni)
            bF[ni] = *(const bf16x8*)&Bs[cur][(wc * 64 + ni * 16 + ln15) * 32 + lg * 8];
        #pragma unroll
        for (int mi = 0; mi < 4; ++mi)
            #pragma unroll
            for (int ni = 0; ni < 4; ++ni)
                acc[mi][ni] = __builtin_amdgcn_mfma_f32_16x16x32_bf16(
                    aF[mi], bF[ni], acc[mi][ni], 0, 0, 0);
        __syncthreads();   // drains stage(it+1) DMA + all reads of buf[cur]
    }

    // epilogue: D col = lane&15 (n), row = (lane>>4)*4 + reg (m)
    #pragma unroll
    for (int ni = 0; ni < 4; ++ni) {
        const int n = n0 + wc * 64 + ni * 16 + ln15;
        const float gv = g[b * C + n];
        float snv = 0.f, bv = 0.f;
        if constexpr (MODE == 2) { snv = sn[n]; bv = bias[n]; }
        #pragma unroll
        for (int mi = 0; mi < 4; ++mi) {
            #pragma unroll
            for (int j = 0; j < 4; ++j) {
                const int m = wr * 64 + mi * 16 + lg * 4 + j;
                int oy, ox;
                if constexpr (MODE == 1) { oy = 2 * (i0 + (m >> 5)) + cla; ox = 2 * (m & 31) + clc; }
                else { oy = oyb * 2 + (m >> 6); ox = m & 63; }
                const size_t idx = ((size_t)((b * HO + oy) * WO + ox) << 9) + n;
                float v = acc[mi][ni][j] * gv;
                if constexpr (MODE == 2) v = lrelu(v + snv * nzs[m] + bv);
                out[idx] = v;
            }
        }
    }
}

// 4x4 FIR blur + noise + bias + lrelu, then fold s2; bf16 into haloed x1buf [8][66][66][512]
__global__ __launch_bounds__(128) void blur_kernel(
    const float* __restrict__ t0, const float* __restrict__ noise1,
    const float* __restrict__ sn1, const float* __restrict__ bias1,
    const float* __restrict__ s2, ushort_t* __restrict__ x1, int b0)
{
    const int ox = blockIdx.x, oy = blockIdx.y, bq = blockIdx.z;
    const int b = b0 + bq;
    const float nz = noise1[(b * HO + oy) * WO + ox];
    const int c = threadIdx.x * 4;
    float a0 = 0.f, a1 = 0.f, a2 = 0.f, a3 = 0.f;
    const float F[4] = {1.f, 3.f, 3.f, 1.f};
    #pragma unroll
    for (int i = 0; i < 4; ++i) {
        int iy = oy + i - 1;
        if ((unsigned)iy >= (unsigned)HO) continue;
        #pragma unroll
        for (int j = 0; j < 4; ++j) {
            int ix = ox + j - 1;
            if ((unsigned)ix >= (unsigned)WO) continue;
            float wgt = F[i] * F[j];
            const float4 v = *(const float4*)&t0[((size_t)((b * HO + iy) * WO + ix) << 9) + c];
            a0 = fmaf(wgt, v.x, a0); a1 = fmaf(wgt, v.y, a1);
            a2 = fmaf(wgt, v.z, a2); a3 = fmaf(wgt, v.w, a3);
        }
    }
    const float4 sv = *(const float4*)&sn1[c];
    const float4 bv = *(const float4*)&bias1[c];
    const float4 s2v = *(const float4*)&s2[b * C + c];
    a0 = lrelu(fmaf(sv.x, nz, a0 * 0.0625f) + bv.x) * s2v.x;
    a1 = lrelu(fmaf(sv.y, nz, a1 * 0.0625f) + bv.y) * s2v.y;
    a2 = lrelu(fmaf(sv.z, nz, a2 * 0.0625f) + bv.z) * s2v.z;
    a3 = lrelu(fmaf(sv.w, nz, a3 * 0.0625f) + bv.w) * s2v.w;
    int2 pk;
    pk.x = (int)f2bu(a0) | ((int)f2bu(a1) << 16);
    pk.y = (int)f2bu(a2) | ((int)f2bu(a3) << 16);
    *(int2*)&x1[(((size_t)bq * 66 + oy + 1) * 66 + ox + 1) * 512 + c] = pk;
}

// 1x1 conv (no demod) + bias + lrelu -> rgb (fp32). Recomputes its own style vector
// so it never reads the d_out-tail scratch it overwrites.
__global__ __launch_bounds__(256) void torgb_kernel(
    const float* __restrict__ x2, const float* __restrict__ w,
    const float* __restrict__ fw, const float* __restrict__ fb,
    const float* __restrict__ wr, const float* __restrict__ biasr,
    float* __restrict__ rgb)
{
    const int b = blockIdx.y;
    const int oy = blockIdx.x * 4 + (threadIdx.x >> 6);
    const int ox = threadIdx.x & 63;
    __shared__ float wrow[C];
    __shared__ float weff[C][3];
    for (int i = threadIdx.x; i < C; i += 256) wrow[i] = w[b * C + i];
    __syncthreads();
    const float scale = 0.044194173824159216f;  // 1/sqrt(512), fc scale AND 1x1 conv wscale
    for (int ci = threadIdx.x; ci < C; ci += 256) {
        float acc = 0.f;
        for (int k = 0; k < C; k++)
            acc = fmaf(wrow[k], fw[k * C + ci], acc);
        float s = acc * scale + fb[ci];
        float sc = scale * s;
        weff[ci][0] = sc * wr[ci * 3 + 0];
        weff[ci][1] = sc * wr[ci * 3 + 1];
        weff[ci][2] = sc * wr[ci * 3 + 2];
    }
    __syncthreads();
    const float* px = x2 + ((size_t)(b * HO + oy) * WO + ox) * C;
    float a0 = 0.f, a1 = 0.f, a2 = 0.f;
    for (int ci = 0; ci < C; ci++) {
        float f = px[ci];
        a0 = fmaf(f, weff[ci][0], a0);
        a1 = fmaf(f, weff[ci][1], a1);
        a2 = fmaf(f, weff[ci][2], a2);
    }
    float* dst = rgb + ((size_t)(b * HO + oy) * WO + ox) * 3;
    dst[0] = lrelu(a0 + biasr[0]);
    dst[1] = lrelu(a1 + biasr[1]);
    dst[2] = lrelu(a2 + biasr[2]);
}

extern "C" void kernel_launch(void* const* d_in, const int* in_sizes, int n_in,
                              void* d_out, int out_size, void* d_ws, size_t ws_size,
                              hipStream_t stream)
{
    (void)in_sizes; (void)n_in; (void)out_size; (void)ws_size;
    const float* x       = (const float*)d_in[0];
    const float* w       = (const float*)d_in[1];
    const float* noise1  = (const float*)d_in[2];
    const float* noise2  = (const float*)d_in[3];
    const float* fcl1_w  = (const float*)d_in[4];
    const float* fcl1_b  = (const float*)d_in[5];
    const float* conv1_w = (const float*)d_in[6];
    const float* sn1     = (const float*)d_in[7];
    const float* bias1   = (const float*)d_in[8];
    const float* fcl2_w  = (const float*)d_in[9];
    const float* fcl2_b  = (const float*)d_in[10];
    const float* conv2_w = (const float*)d_in[11];
    const float* sn2     = (const float*)d_in[12];
    const float* bias2   = (const float*)d_in[13];
    const float* fclr_w  = (const float*)d_in[14];
    const float* fclr_b  = (const float*)d_in[15];
    const float* convr_w = (const float*)d_in[16];
    const float* biasr   = (const float*)d_in[17];

    float* out_x2  = (float*)d_out;               // 16*64*64*512 fp32 = 128 MiB
    float* out_rgb = out_x2 + 33554432;           // 16*64*64*3 fp32 = 768 KiB

    // Scratch in the rgb tail (dead until torgb; torgb only WRITES there): 128 KiB.
    float* s1 = out_rgb;
    float* s2 = out_rgb + 8192;
    float* g1 = out_rgb + 16384;
    float* g2 = out_rgb + 24576;

    // preQ scratch in the t0 region (dead until conv1 writes t0; demod runs first)
    float* q1 = out_x2;              // 1 MiB
    float* q2 = out_x2 + 262144;     // 1 MiB

    // d_ws layout (63 MiB of the guaranteed 64):
    //   wb1  [0,       4.5Mi)  prepped conv1 weights (live until conv1 done)
    //   wb2  [4.5Mi,   9.0Mi)  prepped conv2 weights (live until conv2 done)
    //   xsp  [9.0Mi,  26.0Mi)  bf16 x*s1 haloed [16][33][33][512]
    //   x1b  [26.0Mi, 60.1Mi)  bf16 x1*s2 haloed [8][66][66][512], half-batch ping
    ushort_t* wb1 = (ushort_t*)d_ws;
    ushort_t* wb2 = wb1 + 2359296;                   // 9*16*512*32
    ushort_t* xsp = wb1 + 4718592;
    ushort_t* x1b = xsp + 8921088;                   // 16*33*33*512

    float* t0 = out_x2;  // pre-blur conv1 output (fp32), overwritten by x2 later

    const float WS33 = 0.014731391274719739f;     // 1/sqrt(9*512)

    style_fc_kernel<<<NB, 256, 0, stream>>>(w, fcl1_w, fcl1_b, s1);
    style_fc_kernel<<<NB, 256, 0, stream>>>(w, fcl2_w, fcl2_b, s2);
    wprep_kernel<<<dim3(8, 16), 256, 0, stream>>>(conv1_w, wb1, q1);
    wprep_kernel<<<dim3(8, 16), 256, 0, stream>>>(conv2_w, wb2, q2);
    demod2_kernel<<<dim3(2, NB), 256, 0, stream>>>(s1, q1, g1, WS33);
    demod2_kernel<<<dim3(2, NB), 256, 0, stream>>>(s2, q2, g2, WS33);
    xprep_kernel<<<dim3(33, 33, NB), 128, 0, stream>>>(x, s1, xsp);
    zero_kernel<<<8713, 256, 0, stream>>>((int4*)x1b, 2230272);   // 8*66*66*512*2B /16

    conv_mfma<1><<<dim3(4, 32, NB), 256, 0, stream>>>(
        xsp, wb1, g1, nullptr, nullptr, nullptr, t0, 0);

    for (int half = 0; half < 2; ++half) {
        // blur(half) consumes t0[b in half] before conv2(half) overwrites that region
        blur_kernel<<<dim3(WO, HO, 8), 128, 0, stream>>>(
            t0, noise1, sn1, bias1, s2, x1b, half * 8);
        conv_mfma<2><<<dim3(4, 32, 8), 256, 0, stream>>>(
            x1b, wb2, g2, noise2, sn2, bias2, out_x2, half * 8);
    }

    torgb_kernel<<<dim3(16, NB), 256, 0, stream>>>(out_x2, w, fclr_w, fclr_b, convr_w, biasr, out_rgb);
}

// Round 3
// 1103.219 us; speedup vs baseline: 8.5709x; 1.0455x over previous
//
#include <hip/hip_runtime.h>
#include <hip/hip_bf16.h>

typedef __hip_bfloat16 bf16;
typedef __attribute__((ext_vector_type(8))) __bf16 bf16x8;
typedef __attribute__((ext_vector_type(4))) float f32x4;
typedef unsigned short ushort_t;

#define NB   16
#define HIN  32
#define WIN_ 32
#define C    512
#define HO   64
#define WO   64

__device__ __forceinline__ float lrelu(float v) { return v > 0.f ? v : 0.2f * v; }
__device__ __forceinline__ unsigned short f2bu(float f) {
    union { __hip_bfloat16 h; unsigned short u; } cv;
    cv.h = __float2bfloat16(f);
    return cv.u;
}
// async global->LDS, 16B per lane; lds base must be wave-uniform (lane writes +lane*16B)
__device__ __forceinline__ void gload16(const ushort_t* g, ushort_t* l) {
    __builtin_amdgcn_global_load_lds(
        (const __attribute__((address_space(1))) void*)g,
        (__attribute__((address_space(3))) void*)l, 16, 0, 0);
}

// s[b,co] = sum_ci w[b,ci]*fw[ci,co]*scale + fb[co]
__global__ __launch_bounds__(256) void style_fc_kernel(
    const float* __restrict__ w, const float* __restrict__ fw,
    const float* __restrict__ fb, float* __restrict__ s)
{
    int b = blockIdx.x;
    __shared__ float wrow[C];
    for (int i = threadIdx.x; i < C; i += 256) wrow[i] = w[b * C + i];
    __syncthreads();
    const float scale = 0.044194173824159216f;  // 1/sqrt(512)
    for (int co = threadIdx.x; co < C; co += 256) {
        float acc = 0.f;
        for (int ci = 0; ci < C; ci++)
            acc = fmaf(wrow[ci], fw[ci * C + co], acc);
        s[b * C + co] = acc * scale + fb[co];
    }
}

// One pass over a weight tensor: emit (a) bf16 transposed layout
// wb[t][ct][n=co][kk=ci&31] ready for global_load_lds staging, (b) q[ci][co]=sum_t w^2.
__global__ __launch_bounds__(256) void wprep_kernel(
    const float* __restrict__ cw, ushort_t* __restrict__ wb,
    float* __restrict__ q)
{
    const int nc = blockIdx.x;   // co block of 64
    const int ct = blockIdx.y;   // ci block of 32
    const int tid = threadIdx.x;
    __shared__ float tile[32][65];
    float qacc[8];
    #pragma unroll
    for (int p = 0; p < 8; ++p) qacc[p] = 0.f;
    const int rr = tid >> 6;        // 0..3 (read row within pass)
    const int cc = tid & 63;        // 0..63 (read col)
    const int n  = tid >> 2;        // 0..63 (write col)
    const int kq = tid & 3;         // write kk quad -> kk = kq*8..+7
    for (int t = 0; t < 9; ++t) {
        #pragma unroll
        for (int p = 0; p < 8; ++p) {
            const int r = p * 4 + rr;
            float v = cw[((size_t)(t * C + ct * 32 + r)) * C + nc * 64 + cc];
            tile[r][cc] = v;
            qacc[p] = fmaf(v, v, qacc[p]);
        }
        __syncthreads();
        unsigned int d[4];
        #pragma unroll
        for (int j2 = 0; j2 < 4; ++j2)
            d[j2] = (unsigned int)f2bu(tile[kq * 8 + 2 * j2][n])
                  | ((unsigned int)f2bu(tile[kq * 8 + 2 * j2 + 1][n]) << 16);
        int4 w4 = { (int)d[0], (int)d[1], (int)d[2], (int)d[3] };
        *(int4*)&wb[(((size_t)t * 16 + ct) * 512 + nc * 64 + n) * 32 + kq * 8] = w4;
        __syncthreads();
    }
    #pragma unroll
    for (int p = 0; p < 8; ++p)
        q[(ct * 32 + p * 4 + rr) * C + nc * 64 + cc] = qacc[p];
}

// g[b,co] = wscale * rsqrt(wscale^2 * sum_ci q[ci][co]*s^2[b][ci] + 1e-8)
__global__ __launch_bounds__(256) void demod2_kernel(
    const float* __restrict__ s, const float* __restrict__ q,
    float* __restrict__ g, float wscale)
{
    const int b = blockIdx.y;
    const int co = blockIdx.x * 256 + threadIdx.x;
    __shared__ float s2[C];
    for (int i = threadIdx.x; i < C; i += 256) {
        float v = s[b * C + i];
        s2[i] = v * v;
    }
    __syncthreads();
    float acc = 0.f;
    for (int ci = 0; ci < C; ++ci)
        acc = fmaf(q[ci * C + co], s2[ci], acc);
    g[b * C + co] = wscale / sqrtf(acc * wscale * wscale + 1e-8f);
}

// x*s1 -> bf16, padded [16][33][33][512] with zero halo at iy=0 / ix=0
__global__ __launch_bounds__(128) void xprep_kernel(
    const float* __restrict__ x, const float* __restrict__ s1,
    ushort_t* __restrict__ xp)
{
    const int ix = blockIdx.x;   // 0..32
    const int iy = blockIdx.y;   // 0..32
    const int b  = blockIdx.z;
    const int c  = threadIdx.x * 4;
    int2 pk{0, 0};
    if (iy > 0 && ix > 0) {
        const float4 xv = *(const float4*)&x[(((size_t)b * HIN + iy - 1) * WIN_ + ix - 1) * C + c];
        const float4 sv = *(const float4*)&s1[b * C + c];
        pk.x = (int)f2bu(xv.x * sv.x) | ((int)f2bu(xv.y * sv.y) << 16);
        pk.y = (int)f2bu(xv.z * sv.z) | ((int)f2bu(xv.w * sv.w) << 16);
    }
    *(int2*)&xp[(((size_t)b * 33 + iy) * 33 + ix) * 512 + c] = pk;
}

__global__ __launch_bounds__(256) void zero_kernel(int4* __restrict__ p, int n16)
{
    int i = blockIdx.x * 256 + threadIdx.x;
    int4 z{0, 0, 0, 0};
    if (i < n16) p[i] = z;
}

// Implicit-GEMM MFMA conv, 2-phase double-buffered, all staging via global_load_lds.
// MODE 1: transposed 3x3 s2 conv restructured into parity classes (gy = class*8+iblock);
//   input = prepped bf16 x*s1 with halo [16][33][33][512]; out = t0 fp32, epilogue *g.
// MODE 2: 3x3 s1 conv; input = haloed bf16 x1*s2 [8][66][66][512]; epilogue *g+noise+bias+lrelu.
// Tile M=128 x N=128 x BK=32; 4 waves 2x2; per wave 4x4 frags of mfma_f32_16x16x32_bf16.
// LDS tiles [row][4 granules of 8k], granule (m,q) swizzled to slot q^((m>>1)&3):
//   write side = pre-swizzled global source lane->addr (DMA dest stays linear, rule #21),
//   read side  = frag addr uses lg^((ln15>>1)&3). Every 8-lane octet then covers all 8
//   four-bank groups exactly once -> conflict-free ds_read_b128.
// Grid id is XCD-swizzled (bijective, nwg%8==0) so each XCD owns one batch image.
template<int MODE>
__global__ __launch_bounds__(256) void conv_mfma(
    const ushort_t* __restrict__ xin, const ushort_t* __restrict__ wb,
    const float* __restrict__ g,
    const float* __restrict__ noise, const float* __restrict__ sn,
    const float* __restrict__ bias, float* __restrict__ out, int b0)
{
    // ---- XCD-aware bijective block swizzle (T1): nwg = 4*32*gridZ, %8 == 0 ----
    const int id  = blockIdx.x + 4 * (blockIdx.y + 32 * blockIdx.z);
    const int cpx = 16 * gridDim.z;               // nwg/8
    const int nid = (id & 7) * cpx + (id >> 3);
    const int n0 = (nid & 3) * 128;
    const int gy = (nid >> 2) & 31;
    const int bz = nid >> 7;
    const int b  = b0 + bz;

    const int tid = threadIdx.x;
    const int lane = tid & 63, wave = tid >> 6;
    const int wr = wave >> 1, wc = wave & 1;
    const int ln15 = lane & 15, lg = lane >> 4;

    __shared__ ushort_t As[2][4096];
    __shared__ ushort_t Bs[2][4096];
    __shared__ float nzs[128];

    int ntap = 9;
    int i0 = 0, cla = 0, clc = 0, oyb = 0, nkx = 1;
    if constexpr (MODE == 1) {
        const int cl = gy >> 3;
        i0 = (gy & 7) * 4;
        cla = cl >> 1; clc = cl & 1;
        const int nky = (cla == 0) ? 2 : 1;
        nkx = (clc == 0) ? 2 : 1;
        ntap = nky * nkx;
    } else {
        oyb = gy;
        if (tid < 128)
            nzs[tid] = noise[(b * HO + oyb * 2 + (tid >> 6)) * WO + (tid & 63)];
    }

    // per-thread global bases (element units), granule-swizzled: q_src = (s&3)^((s>>3)&3)
    int abase[2], bbase[2];
    #pragma unroll
    for (int i2 = 0; i2 < 2; ++i2) {
        const int s = tid + 256 * i2;
        const int m = s >> 2;
        const int qs = (s & 3) ^ ((s >> 3) & 3);
        if constexpr (MODE == 2) {
            abase[i2] = ((bz * 66 + oyb * 2 + (m >> 6)) * 66 + (m & 63)) * 512 + qs * 8;
        } else {
            abase[i2] = ((b * 33 + i0 + (m >> 5) + 1) * 33 + (m & 31) + 1) * 512 + qs * 8;
        }
        bbase[i2] = n0 * 32 + (s >> 2) * 32 + qs * 8;
    }
    const int ldso[2] = { wave * 512, wave * 512 + 2048 };

    auto issue = [&](int bufi, int ao, int bo) {
        #pragma unroll
        for (int i2 = 0; i2 < 2; ++i2) {
            gload16(xin + abase[i2] + ao, &As[bufi][ldso[i2]]);
            gload16(wb + bo + bbase[i2], &Bs[bufi][ldso[i2]]);
        }
    };

    // tap offset helper (wave-uniform SALU; runs once per 16 steps)
    auto tap1 = [&](int u, int v, int& ao, int& bo) {
        const int ky = (cla == 0) ? 2 * u : 1;
        const int kx = (clc == 0) ? 2 * v : 1;
        const int dy = (cla + ky - 2) >> 1, dx = (clc + kx - 2) >> 1;
        ao = (dy * 33 + dx) * 512;
        bo = (ky * 3 + kx) * 262144;
    };

    // hoisted, loop-invariant fragment LDS addresses (element units)
    const int sa = (ln15 >> 1) & 3;
    const int fs = (lg ^ sa) * 8;
    int ra[4], rb[4];
    #pragma unroll
    for (int i = 0; i < 4; ++i) {
        ra[i] = (wr * 64 + i * 16 + ln15) * 32 + fs;
        rb[i] = (wc * 64 + i * 16 + ln15) * 32 + fs;
    }

    f32x4 acc[4][4];
    #pragma unroll
    for (int i = 0; i < 4; ++i)
        #pragma unroll
        for (int j = 0; j < 4; ++j) {
            f32x4 z = {0.f, 0.f, 0.f, 0.f};
            acc[i][j] = z;
        }

    // stage-side state (wave-uniform)
    int s_ci = 0, s_u = 0, s_v = 0, s_ky = 0, s_kx = 0;
    int s_ao, s_bo;
    if constexpr (MODE == 1) tap1(0, 0, s_ao, s_bo);
    else { s_ao = 0; s_bo = 0; }

    const int nstep = ntap * 16;
    issue(0, s_ao, s_bo);
    __syncthreads();   // drains vmcnt(0): buf0 ready (and nzs visible)

    for (int it = 0; it < nstep; ++it) {
        const int cur = it & 1;
        if (it + 1 < nstep) {
            // advance stage state to step it+1 (incremental; tap recompute 1/16 steps)
            ++s_ci;
            s_ao += 32; s_bo += 16384;
            if (s_ci == 16) {
                s_ci = 0;
                if constexpr (MODE == 1) {
                    if (++s_v == nkx) { s_v = 0; ++s_u; }
                    tap1(s_u, s_v, s_ao, s_bo);
                } else {
                    if (++s_kx == 3) { s_kx = 0; ++s_ky; }
                    s_ao = (s_ky * 66 + s_kx) * 512;
                    s_bo = (s_ky * 3 + s_kx) * 262144;
                }
            }
            issue(cur ^ 1, s_ao, s_bo);
        }
        const ushort_t* __restrict__ curA = As[cur];
        const ushort_t* __restrict__ curB = Bs[cur];
        bf16x8 aF[4], bF[4];
        #pragma unroll
        for (int mi = 0; mi < 4; ++mi)
            aF[mi] = *(const bf16x8*)&curA[ra[mi]];
        #pragma unroll
        for (int ni = 0; ni < 4; ++ni)
            bF[ni] = *(const bf16x8*)&curB[rb[ni]];
        #pragma unroll
        for (int mi = 0; mi < 4; ++mi)
            #pragma unroll
            for (int ni = 0; ni < 4; ++ni)
                acc[mi][ni] = __builtin_amdgcn_mfma_f32_16x16x32_bf16(
                    aF[mi], bF[ni], acc[mi][ni], 0, 0, 0);
        __syncthreads();   // drains stage(it+1) DMA + all reads of buf[cur]
    }

    // epilogue: D col = lane&15 (n), row = (lane>>4)*4 + reg (m)
    #pragma unroll
    for (int ni = 0; ni < 4; ++ni) {
        const int n = n0 + wc * 64 + ni * 16 + ln15;
        const float gv = g[b * C + n];
        float snv = 0.f, bv = 0.f;
        if constexpr (MODE == 2) { snv = sn[n]; bv = bias[n]; }
        #pragma unroll
        for (int mi = 0; mi < 4; ++mi) {
            #pragma unroll
            for (int j = 0; j < 4; ++j) {
                const int m = wr * 64 + mi * 16 + lg * 4 + j;
                int oy, ox;
                if constexpr (MODE == 1) { oy = 2 * (i0 + (m >> 5)) + cla; ox = 2 * (m & 31) + clc; }
                else { oy = oyb * 2 + (m >> 6); ox = m & 63; }
                const size_t idx = ((size_t)((b * HO + oy) * WO + ox) << 9) + n;
                float v = acc[mi][ni][j] * gv;
                if constexpr (MODE == 2) v = lrelu(v + snv * nzs[m] + bv);
                out[idx] = v;
            }
        }
    }
}

// 4x4 FIR blur + noise + bias + lrelu, then fold s2; bf16 into haloed x1buf [8][66][66][512]
__global__ __launch_bounds__(128) void blur_kernel(
    const float* __restrict__ t0, const float* __restrict__ noise1,
    const float* __restrict__ sn1, const float* __restrict__ bias1,
    const float* __restrict__ s2, ushort_t* __restrict__ x1, int b0)
{
    const int ox = blockIdx.x, oy = blockIdx.y, bq = blockIdx.z;
    const int b = b0 + bq;
    const float nz = noise1[(b * HO + oy) * WO + ox];
    const int c = threadIdx.x * 4;
    float a0 = 0.f, a1 = 0.f, a2 = 0.f, a3 = 0.f;
    const float F[4] = {1.f, 3.f, 3.f, 1.f};
    #pragma unroll
    for (int i = 0; i < 4; ++i) {
        int iy = oy + i - 1;
        if ((unsigned)iy >= (unsigned)HO) continue;
        #pragma unroll
        for (int j = 0; j < 4; ++j) {
            int ix = ox + j - 1;
            if ((unsigned)ix >= (unsigned)WO) continue;
            float wgt = F[i] * F[j];
            const float4 v = *(const float4*)&t0[((size_t)((b * HO + iy) * WO + ix) << 9) + c];
            a0 = fmaf(wgt, v.x, a0); a1 = fmaf(wgt, v.y, a1);
            a2 = fmaf(wgt, v.z, a2); a3 = fmaf(wgt, v.w, a3);
        }
    }
    const float4 sv = *(const float4*)&sn1[c];
    const float4 bv = *(const float4*)&bias1[c];
    const float4 s2v = *(const float4*)&s2[b * C + c];
    a0 = lrelu(fmaf(sv.x, nz, a0 * 0.0625f) + bv.x) * s2v.x;
    a1 = lrelu(fmaf(sv.y, nz, a1 * 0.0625f) + bv.y) * s2v.y;
    a2 = lrelu(fmaf(sv.z, nz, a2 * 0.0625f) + bv.z) * s2v.z;
    a3 = lrelu(fmaf(sv.w, nz, a3 * 0.0625f) + bv.w) * s2v.w;
    int2 pk;
    pk.x = (int)f2bu(a0) | ((int)f2bu(a1) << 16);
    pk.y = (int)f2bu(a2) | ((int)f2bu(a3) << 16);
    *(int2*)&x1[(((size_t)bq * 66 + oy + 1) * 66 + ox + 1) * 512 + c] = pk;
}

// 1x1 conv (no demod) + bias + lrelu -> rgb (fp32). Recomputes its own style vector
// so it never reads the d_out-tail scratch it overwrites.
__global__ __launch_bounds__(256) void torgb_kernel(
    const float* __restrict__ x2, const float* __restrict__ w,
    const float* __restrict__ fw, const float* __restrict__ fb,
    const float* __restrict__ wr, const float* __restrict__ biasr,
    float* __restrict__ rgb)
{
    const int b = blockIdx.y;
    const int oy = blockIdx.x * 4 + (threadIdx.x >> 6);
    const int ox = threadIdx.x & 63;
    __shared__ float wrow[C];
    __shared__ float weff[C][3];
    for (int i = threadIdx.x; i < C; i += 256) wrow[i] = w[b * C + i];
    __syncthreads();
    const float scale = 0.044194173824159216f;  // 1/sqrt(512), fc scale AND 1x1 conv wscale
    for (int ci = threadIdx.x; ci < C; ci += 256) {
        float acc = 0.f;
        for (int k = 0; k < C; k++)
            acc = fmaf(wrow[k], fw[k * C + ci], acc);
        float s = acc * scale + fb[ci];
        float sc = scale * s;
        weff[ci][0] = sc * wr[ci * 3 + 0];
        weff[ci][1] = sc * wr[ci * 3 + 1];
        weff[ci][2] = sc * wr[ci * 3 + 2];
    }
    __syncthreads();
    const float* px = x2 + ((size_t)(b * HO + oy) * WO + ox) * C;
    float a0 = 0.f, a1 = 0.f, a2 = 0.f;
    for (int ci = 0; ci < C; ci++) {
        float f = px[ci];
        a0 = fmaf(f, weff[ci][0], a0);
        a1 = fmaf(f, weff[ci][1], a1);
        a2 = fmaf(f, weff[ci][2], a2);
    }
    float* dst = rgb + ((size_t)(b * HO + oy) * WO + ox) * 3;
    dst[0] = lrelu(a0 + biasr[0]);
    dst[1] = lrelu(a1 + biasr[1]);
    dst[2] = lrelu(a2 + biasr[2]);
}

extern "C" void kernel_launch(void* const* d_in, const int* in_sizes, int n_in,
                              void* d_out, int out_size, void* d_ws, size_t ws_size,
                              hipStream_t stream)
{
    (void)in_sizes; (void)n_in; (void)out_size; (void)ws_size;
    const float* x       = (const float*)d_in[0];
    const float* w       = (const float*)d_in[1];
    const float* noise1  = (const float*)d_in[2];
    const float* noise2  = (const float*)d_in[3];
    const float* fcl1_w  = (const float*)d_in[4];
    const float* fcl1_b  = (const float*)d_in[5];
    const float* conv1_w = (const float*)d_in[6];
    const float* sn1     = (const float*)d_in[7];
    const float* bias1   = (const float*)d_in[8];
    const float* fcl2_w  = (const float*)d_in[9];
    const float* fcl2_b  = (const float*)d_in[10];
    const float* conv2_w = (const float*)d_in[11];
    const float* sn2     = (const float*)d_in[12];
    const float* bias2   = (const float*)d_in[13];
    const float* fclr_w  = (const float*)d_in[14];
    const float* fclr_b  = (const float*)d_in[15];
    const float* convr_w = (const float*)d_in[16];
    const float* biasr   = (const float*)d_in[17];

    float* out_x2  = (float*)d_out;               // 16*64*64*512 fp32 = 128 MiB
    float* out_rgb = out_x2 + 33554432;           // 16*64*64*3 fp32 = 768 KiB

    // Scratch in the rgb tail (dead until torgb; torgb only WRITES there): 128 KiB.
    float* s1 = out_rgb;
    float* s2 = out_rgb + 8192;
    float* g1 = out_rgb + 16384;
    float* g2 = out_rgb + 24576;

    // preQ scratch in the t0 region (dead until conv1 writes t0; demod runs first)
    float* q1 = out_x2;              // 1 MiB
    float* q2 = out_x2 + 262144;     // 1 MiB

    // d_ws layout (63 MiB of the guaranteed 64):
    //   wb1  [0,       4.5Mi)  prepped conv1 weights (live until conv1 done)
    //   wb2  [4.5Mi,   9.0Mi)  prepped conv2 weights (live until conv2 done)
    //   xsp  [9.0Mi,  26.0Mi)  bf16 x*s1 haloed [16][33][33][512]
    //   x1b  [26.0Mi, 60.1Mi)  bf16 x1*s2 haloed [8][66][66][512], half-batch ping
    ushort_t* wb1 = (ushort_t*)d_ws;
    ushort_t* wb2 = wb1 + 2359296;                   // 9*16*512*32
    ushort_t* xsp = wb1 + 4718592;
    ushort_t* x1b = xsp + 8921088;                   // 16*33*33*512

    float* t0 = out_x2;  // pre-blur conv1 output (fp32), overwritten by x2 later

    const float WS33 = 0.014731391274719739f;     // 1/sqrt(9*512)

    style_fc_kernel<<<NB, 256, 0, stream>>>(w, fcl1_w, fcl1_b, s1);
    style_fc_kernel<<<NB, 256, 0, stream>>>(w, fcl2_w, fcl2_b, s2);
    wprep_kernel<<<dim3(8, 16), 256, 0, stream>>>(conv1_w, wb1, q1);
    wprep_kernel<<<dim3(8, 16), 256, 0, stream>>>(conv2_w, wb2, q2);
    demod2_kernel<<<dim3(2, NB), 256, 0, stream>>>(s1, q1, g1, WS33);
    demod2_kernel<<<dim3(2, NB), 256, 0, stream>>>(s2, q2, g2, WS33);
    xprep_kernel<<<dim3(33, 33, NB), 128, 0, stream>>>(x, s1, xsp);
    zero_kernel<<<8713, 256, 0, stream>>>((int4*)x1b, 2230272);   // 8*66*66*512*2B /16

    conv_mfma<1><<<dim3(4, 32, NB), 256, 0, stream>>>(
        xsp, wb1, g1, nullptr, nullptr, nullptr, t0, 0);

    for (int half = 0; half < 2; ++half) {
        // blur(half) consumes t0[b in half] before conv2(half) overwrites that region
        blur_kernel<<<dim3(WO, HO, 8), 128, 0, stream>>>(
            t0, noise1, sn1, bias1, s2, x1b, half * 8);
        conv_mfma<2><<<dim3(4, 32, 8), 256, 0, stream>>>(
            x1b, wb2, g2, noise2, sn2, bias2, out_x2, half * 8);
    }

    torgb_kernel<<<dim3(16, NB), 256, 0, stream>>>(out_x2, w, fclr_w, fclr_b, convr_w, biasr, out_rgb);
}

// Round 4
// 936.790 us; speedup vs baseline: 10.0936x; 1.1777x over previous
//
#include <hip/hip_runtime.h>
#include <hip/hip_bf16.h>

typedef __hip_bfloat16 bf16;
typedef __attribute__((ext_vector_type(8))) __bf16 bf16x8;
typedef __attribute__((ext_vector_type(4))) float f32x4;
typedef unsigned short ushort_t;

#define NB   16
#define HIN  32
#define WIN_ 32
#define C    512
#define HO   64
#define WO   64

__device__ __forceinline__ float lrelu(float v) { return v > 0.f ? v : 0.2f * v; }
__device__ __forceinline__ unsigned short f2bu(float f) {
    union { __hip_bfloat16 h; unsigned short u; } cv;
    cv.h = __float2bfloat16(f);
    return cv.u;
}
// async global->LDS, 16B per lane; lds base must be wave-uniform (lane writes +lane*16B)
__device__ __forceinline__ void gload16(const ushort_t* g, ushort_t* l) {
    __builtin_amdgcn_global_load_lds(
        (const __attribute__((address_space(1))) void*)g,
        (__attribute__((address_space(3))) void*)l, 16, 0, 0);
}

// s[b,co] = sum_ci w[b,ci]*fw[ci,co]*scale + fb[co]
__global__ __launch_bounds__(256) void style_fc_kernel(
    const float* __restrict__ w, const float* __restrict__ fw,
    const float* __restrict__ fb, float* __restrict__ s)
{
    int b = blockIdx.x;
    __shared__ float wrow[C];
    for (int i = threadIdx.x; i < C; i += 256) wrow[i] = w[b * C + i];
    __syncthreads();
    const float scale = 0.044194173824159216f;  // 1/sqrt(512)
    for (int co = threadIdx.x; co < C; co += 256) {
        float acc = 0.f;
        for (int ci = 0; ci < C; ci++)
            acc = fmaf(wrow[ci], fw[ci * C + co], acc);
        s[b * C + co] = acc * scale + fb[co];
    }
}

// One pass over a weight tensor: emit (a) bf16 transposed layout
// wb[t][ct][n=co][kk=ci&31] ready for global_load_lds staging, (b) q[ci][co]=sum_t w^2.
__global__ __launch_bounds__(256) void wprep_kernel(
    const float* __restrict__ cw, ushort_t* __restrict__ wb,
    float* __restrict__ q)
{
    const int nc = blockIdx.x;   // co block of 64
    const int ct = blockIdx.y;   // ci block of 32
    const int tid = threadIdx.x;
    __shared__ float tile[32][65];
    float qacc[8];
    #pragma unroll
    for (int p = 0; p < 8; ++p) qacc[p] = 0.f;
    const int rr = tid >> 6;        // 0..3 (read row within pass)
    const int cc = tid & 63;        // 0..63 (read col)
    const int n  = tid >> 2;        // 0..63 (write col)
    const int kq = tid & 3;         // write kk quad -> kk = kq*8..+7
    for (int t = 0; t < 9; ++t) {
        #pragma unroll
        for (int p = 0; p < 8; ++p) {
            const int r = p * 4 + rr;
            float v = cw[((size_t)(t * C + ct * 32 + r)) * C + nc * 64 + cc];
            tile[r][cc] = v;
            qacc[p] = fmaf(v, v, qacc[p]);
        }
        __syncthreads();
        unsigned int d[4];
        #pragma unroll
        for (int j2 = 0; j2 < 4; ++j2)
            d[j2] = (unsigned int)f2bu(tile[kq * 8 + 2 * j2][n])
                  | ((unsigned int)f2bu(tile[kq * 8 + 2 * j2 + 1][n]) << 16);
        int4 w4 = { (int)d[0], (int)d[1], (int)d[2], (int)d[3] };
        *(int4*)&wb[(((size_t)t * 16 + ct) * 512 + nc * 64 + n) * 32 + kq * 8] = w4;
        __syncthreads();
    }
    #pragma unroll
    for (int p = 0; p < 8; ++p)
        q[(ct * 32 + p * 4 + rr) * C + nc * 64 + cc] = qacc[p];
}

// g[b,co] = wscale * rsqrt(wscale^2 * sum_ci q[ci][co]*s^2[b][ci] + 1e-8)
__global__ __launch_bounds__(256) void demod2_kernel(
    const float* __restrict__ s, const float* __restrict__ q,
    float* __restrict__ g, float wscale)
{
    const int b = blockIdx.y;
    const int co = blockIdx.x * 256 + threadIdx.x;
    __shared__ float s2[C];
    for (int i = threadIdx.x; i < C; i += 256) {
        float v = s[b * C + i];
        s2[i] = v * v;
    }
    __syncthreads();
    float acc = 0.f;
    for (int ci = 0; ci < C; ++ci)
        acc = fmaf(q[ci * C + co], s2[ci], acc);
    g[b * C + co] = wscale / sqrtf(acc * wscale * wscale + 1e-8f);
}

// x*s1 -> bf16, padded [16][33][33][512] with zero halo at iy=0 / ix=0
__global__ __launch_bounds__(128) void xprep_kernel(
    const float* __restrict__ x, const float* __restrict__ s1,
    ushort_t* __restrict__ xp)
{
    const int ix = blockIdx.x;   // 0..32
    const int iy = blockIdx.y;   // 0..32
    const int b  = blockIdx.z;
    const int c  = threadIdx.x * 4;
    int2 pk{0, 0};
    if (iy > 0 && ix > 0) {
        const float4 xv = *(const float4*)&x[(((size_t)b * HIN + iy - 1) * WIN_ + ix - 1) * C + c];
        const float4 sv = *(const float4*)&s1[b * C + c];
        pk.x = (int)f2bu(xv.x * sv.x) | ((int)f2bu(xv.y * sv.y) << 16);
        pk.y = (int)f2bu(xv.z * sv.z) | ((int)f2bu(xv.w * sv.w) << 16);
    }
    *(int2*)&xp[(((size_t)b * 33 + iy) * 33 + ix) * 512 + c] = pk;
}

__global__ __launch_bounds__(256) void zero_kernel(int4* __restrict__ p, int n16)
{
    int i = blockIdx.x * 256 + threadIdx.x;
    int4 z{0, 0, 0, 0};
    if (i < n16) p[i] = z;
}

// Implicit-GEMM MFMA conv. 4-slot LDS ring, prefetch distance 2, counted vmcnt
// (T3+T4): per step [issue stage(it+2); s_waitcnt vmcnt(8); s_barrier; ds_read
// frags; setprio(1); 16 MFMA; setprio(0)]. vmcnt never drains to 0 in steady
// state; tail uses 4 then 0. Race-safety: stage(it+2) overwrites the buffer read
// at step it-2; barrier(it-1) separates every reader from that writer. Each wave's
// counted vmcnt before barrier(it) guarantees its own DMA for buf[it] landed.
// MODE 1: transposed 3x3 s2 conv as parity classes (gy = class*8+iblock);
//   input = prepped bf16 x*s1 halo [16][33][33][512]; out = t0 fp32, epilogue *g.
// MODE 2: 3x3 s1 conv; input = haloed bf16 x1*s2 [8][66][66][512]; epilogue
//   *g + noise + bias + lrelu.
// Tile M=128 x N=128 x BK=32; 4 waves 2x2; per wave 4x4 frags of mfma 16x16x32.
// LDS granule swizzle slot q^((m>>1)&3) via pre-swizzled global source (rule #21);
// read addr uses lg^((ln15>>1)&3) -> conflict-free ds_read_b128 (verified R3: 0).
// Grid id XCD-swizzled (bijective, nwg%8==0).
template<int MODE>
__global__ __launch_bounds__(256) void conv_mfma(
    const ushort_t* __restrict__ xin, const ushort_t* __restrict__ wb,
    const float* __restrict__ g,
    const float* __restrict__ noise, const float* __restrict__ sn,
    const float* __restrict__ bias, float* __restrict__ out, int b0)
{
    // ---- XCD-aware bijective block swizzle (T1): nwg = 4*32*gridZ, %8 == 0 ----
    const int id  = blockIdx.x + 4 * (blockIdx.y + 32 * blockIdx.z);
    const int cpx = 16 * gridDim.z;               // nwg/8
    const int nid = (id & 7) * cpx + (id >> 3);
    const int n0 = (nid & 3) * 128;
    const int gy = (nid >> 2) & 31;
    const int bz = nid >> 7;
    const int b  = b0 + bz;

    const int tid = threadIdx.x;
    const int lane = tid & 63, wave = tid >> 6;
    const int wr = wave >> 1, wc = wave & 1;
    const int ln15 = lane & 15, lg = lane >> 4;

    __shared__ ushort_t As[4][4096];
    __shared__ ushort_t Bs[4][4096];
    __shared__ float nzs[128];

    int ntap = 9;
    int i0 = 0, cla = 0, clc = 0, oyb = 0, nkx = 1;
    if constexpr (MODE == 1) {
        const int cl = gy >> 3;
        i0 = (gy & 7) * 4;
        cla = cl >> 1; clc = cl & 1;
        const int nky = (cla == 0) ? 2 : 1;
        nkx = (clc == 0) ? 2 : 1;
        ntap = nky * nkx;
    } else {
        oyb = gy;
        if (tid < 128)
            nzs[tid] = noise[(b * HO + oyb * 2 + (tid >> 6)) * WO + (tid & 63)];
    }

    // per-thread global bases (element units), granule-swizzled: q_src = (s&3)^((s>>3)&3)
    int abase[2], bbase[2];
    #pragma unroll
    for (int i2 = 0; i2 < 2; ++i2) {
        const int s = tid + 256 * i2;
        const int m = s >> 2;
        const int qs = (s & 3) ^ ((s >> 3) & 3);
        if constexpr (MODE == 2) {
            abase[i2] = ((bz * 66 + oyb * 2 + (m >> 6)) * 66 + (m & 63)) * 512 + qs * 8;
        } else {
            abase[i2] = ((b * 33 + i0 + (m >> 5) + 1) * 33 + (m & 31) + 1) * 512 + qs * 8;
        }
        bbase[i2] = n0 * 32 + (s >> 2) * 32 + qs * 8;
    }
    const int ldso[2] = { wave * 512, wave * 512 + 2048 };

    auto issue = [&](int bufi, int ao, int bo) {
        #pragma unroll
        for (int i2 = 0; i2 < 2; ++i2) {
            gload16(xin + abase[i2] + ao, &As[bufi][ldso[i2]]);
            gload16(wb + bo + bbase[i2], &Bs[bufi][ldso[i2]]);
        }
    };

    // tap offset helper (wave-uniform SALU; runs once per 16 steps)
    auto tap1 = [&](int u, int v, int& ao, int& bo) {
        const int ky = (cla == 0) ? 2 * u : 1;
        const int kx = (clc == 0) ? 2 * v : 1;
        const int dy = (cla + ky - 2) >> 1, dx = (clc + kx - 2) >> 1;
        ao = (dy * 33 + dx) * 512;
        bo = (ky * 3 + kx) * 262144;
    };

    // hoisted, loop-invariant fragment LDS addresses (element units)
    const int sa = (ln15 >> 1) & 3;
    const int fs = (lg ^ sa) * 8;
    int ra[4], rb[4];
    #pragma unroll
    for (int i = 0; i < 4; ++i) {
        ra[i] = (wr * 64 + i * 16 + ln15) * 32 + fs;
        rb[i] = (wc * 64 + i * 16 + ln15) * 32 + fs;
    }

    f32x4 acc[4][4];
    #pragma unroll
    for (int i = 0; i < 4; ++i)
        #pragma unroll
        for (int j = 0; j < 4; ++j) {
            f32x4 z = {0.f, 0.f, 0.f, 0.f};
            acc[i][j] = z;
        }

    // stage-side state (wave-uniform), tracks the NEXT stage to issue
    int s_ci = 0, s_u = 0, s_v = 0, s_ky = 0, s_kx = 0;
    int s_ao, s_bo;
    if constexpr (MODE == 1) tap1(0, 0, s_ao, s_bo);
    else { s_ao = 0; s_bo = 0; }

    auto advance = [&]() {
        ++s_ci;
        s_ao += 32; s_bo += 16384;
        if (s_ci == 16) {
            s_ci = 0;
            if constexpr (MODE == 1) {
                if (++s_v == nkx) { s_v = 0; ++s_u; }
                tap1(s_u, s_v, s_ao, s_bo);
            } else {
                if (++s_kx == 3) { s_kx = 0; ++s_ky; }
                s_ao = (s_ky * 66 + s_kx) * 512;
                s_bo = (s_ky * 3 + s_kx) * 262144;
            }
        }
    };

    const int nstep = ntap * 16;   // always >= 16
    issue(0, s_ao, s_bo); advance();
    issue(1, s_ao, s_bo); advance();
    __syncthreads();   // once: drains stages 0-1, publishes nzs

    for (int it = 0; it < nstep; ++it) {
        if (it + 2 < nstep) {
            issue((it + 2) & 3, s_ao, s_bo);
            advance();
            asm volatile("s_waitcnt vmcnt(8)" ::: "memory");
        } else if (it + 1 < nstep) {
            asm volatile("s_waitcnt vmcnt(4)" ::: "memory");
        } else {
            asm volatile("s_waitcnt vmcnt(0)" ::: "memory");
        }
        __builtin_amdgcn_s_barrier();
        __builtin_amdgcn_sched_barrier(0);

        const ushort_t* __restrict__ curA = As[it & 3];
        const ushort_t* __restrict__ curB = Bs[it & 3];
        bf16x8 aF[4], bF[4];
        #pragma unroll
        for (int mi = 0; mi < 4; ++mi)
            aF[mi] = *(const bf16x8*)&curA[ra[mi]];
        #pragma unroll
        for (int ni = 0; ni < 4; ++ni)
            bF[ni] = *(const bf16x8*)&curB[rb[ni]];
        __builtin_amdgcn_s_setprio(1);
        #pragma unroll
        for (int mi = 0; mi < 4; ++mi)
            #pragma unroll
            for (int ni = 0; ni < 4; ++ni)
                acc[mi][ni] = __builtin_amdgcn_mfma_f32_16x16x32_bf16(
                    aF[mi], bF[ni], acc[mi][ni], 0, 0, 0);
        __builtin_amdgcn_s_setprio(0);
    }

    // epilogue: D col = lane&15 (n), row = (lane>>4)*4 + reg (m)
    #pragma unroll
    for (int ni = 0; ni < 4; ++ni) {
        const int n = n0 + wc * 64 + ni * 16 + ln15;
        const float gv = g[b * C + n];
        float snv = 0.f, bv = 0.f;
        if constexpr (MODE == 2) { snv = sn[n]; bv = bias[n]; }
        #pragma unroll
        for (int mi = 0; mi < 4; ++mi) {
            #pragma unroll
            for (int j = 0; j < 4; ++j) {
                const int m = wr * 64 + mi * 16 + lg * 4 + j;
                int oy, ox;
                if constexpr (MODE == 1) { oy = 2 * (i0 + (m >> 5)) + cla; ox = 2 * (m & 31) + clc; }
                else { oy = oyb * 2 + (m >> 6); ox = m & 63; }
                const size_t idx = ((size_t)((b * HO + oy) * WO + ox) << 9) + n;
                float v = acc[mi][ni][j] * gv;
                if constexpr (MODE == 2) v = lrelu(v + snv * nzs[m] + bv);
                out[idx] = v;
            }
        }
    }
}

// 4x4 FIR blur + noise + bias + lrelu, then fold s2; bf16 into haloed x1buf [8][66][66][512]
__global__ __launch_bounds__(128) void blur_kernel(
    const float* __restrict__ t0, const float* __restrict__ noise1,
    const float* __restrict__ sn1, const float* __restrict__ bias1,
    const float* __restrict__ s2, ushort_t* __restrict__ x1, int b0)
{
    const int ox = blockIdx.x, oy = blockIdx.y, bq = blockIdx.z;
    const int b = b0 + bq;
    const float nz = noise1[(b * HO + oy) * WO + ox];
    const int c = threadIdx.x * 4;
    float a0 = 0.f, a1 = 0.f, a2 = 0.f, a3 = 0.f;
    const float F[4] = {1.f, 3.f, 3.f, 1.f};
    #pragma unroll
    for (int i = 0; i < 4; ++i) {
        int iy = oy + i - 1;
        if ((unsigned)iy >= (unsigned)HO) continue;
        #pragma unroll
        for (int j = 0; j < 4; ++j) {
            int ix = ox + j - 1;
            if ((unsigned)ix >= (unsigned)WO) continue;
            float wgt = F[i] * F[j];
            const float4 v = *(const float4*)&t0[((size_t)((b * HO + iy) * WO + ix) << 9) + c];
            a0 = fmaf(wgt, v.x, a0); a1 = fmaf(wgt, v.y, a1);
            a2 = fmaf(wgt, v.z, a2); a3 = fmaf(wgt, v.w, a3);
        }
    }
    const float4 sv = *(const float4*)&sn1[c];
    const float4 bv = *(const float4*)&bias1[c];
    const float4 s2v = *(const float4*)&s2[b * C + c];
    a0 = lrelu(fmaf(sv.x, nz, a0 * 0.0625f) + bv.x) * s2v.x;
    a1 = lrelu(fmaf(sv.y, nz, a1 * 0.0625f) + bv.y) * s2v.y;
    a2 = lrelu(fmaf(sv.z, nz, a2 * 0.0625f) + bv.z) * s2v.z;
    a3 = lrelu(fmaf(sv.w, nz, a3 * 0.0625f) + bv.w) * s2v.w;
    int2 pk;
    pk.x = (int)f2bu(a0) | ((int)f2bu(a1) << 16);
    pk.y = (int)f2bu(a2) | ((int)f2bu(a3) << 16);
    *(int2*)&x1[(((size_t)bq * 66 + oy + 1) * 66 + ox + 1) * 512 + c] = pk;
}

// 1x1 conv (no demod) + bias + lrelu -> rgb (fp32). Recomputes its own style vector
// so it never reads the d_out-tail scratch it overwrites.
__global__ __launch_bounds__(256) void torgb_kernel(
    const float* __restrict__ x2, const float* __restrict__ w,
    const float* __restrict__ fw, const float* __restrict__ fb,
    const float* __restrict__ wr, const float* __restrict__ biasr,
    float* __restrict__ rgb)
{
    const int b = blockIdx.y;
    const int oy = blockIdx.x * 4 + (threadIdx.x >> 6);
    const int ox = threadIdx.x & 63;
    __shared__ float wrow[C];
    __shared__ float weff[C][3];
    for (int i = threadIdx.x; i < C; i += 256) wrow[i] = w[b * C + i];
    __syncthreads();
    const float scale = 0.044194173824159216f;  // 1/sqrt(512), fc scale AND 1x1 conv wscale
    for (int ci = threadIdx.x; ci < C; ci += 256) {
        float acc = 0.f;
        for (int k = 0; k < C; k++)
            acc = fmaf(wrow[k], fw[k * C + ci], acc);
        float s = acc * scale + fb[ci];
        float sc = scale * s;
        weff[ci][0] = sc * wr[ci * 3 + 0];
        weff[ci][1] = sc * wr[ci * 3 + 1];
        weff[ci][2] = sc * wr[ci * 3 + 2];
    }
    __syncthreads();
    const float* px = x2 + ((size_t)(b * HO + oy) * WO + ox) * C;
    float a0 = 0.f, a1 = 0.f, a2 = 0.f;
    for (int ci = 0; ci < C; ci++) {
        float f = px[ci];
        a0 = fmaf(f, weff[ci][0], a0);
        a1 = fmaf(f, weff[ci][1], a1);
        a2 = fmaf(f, weff[ci][2], a2);
    }
    float* dst = rgb + ((size_t)(b * HO + oy) * WO + ox) * 3;
    dst[0] = lrelu(a0 + biasr[0]);
    dst[1] = lrelu(a1 + biasr[1]);
    dst[2] = lrelu(a2 + biasr[2]);
}

extern "C" void kernel_launch(void* const* d_in, const int* in_sizes, int n_in,
                              void* d_out, int out_size, void* d_ws, size_t ws_size,
                              hipStream_t stream)
{
    (void)in_sizes; (void)n_in; (void)out_size; (void)ws_size;
    const float* x       = (const float*)d_in[0];
    const float* w       = (const float*)d_in[1];
    const float* noise1  = (const float*)d_in[2];
    const float* noise2  = (const float*)d_in[3];
    const float* fcl1_w  = (const float*)d_in[4];
    const float* fcl1_b  = (const float*)d_in[5];
    const float* conv1_w = (const float*)d_in[6];
    const float* sn1     = (const float*)d_in[7];
    const float* bias1   = (const float*)d_in[8];
    const float* fcl2_w  = (const float*)d_in[9];
    const float* fcl2_b  = (const float*)d_in[10];
    const float* conv2_w = (const float*)d_in[11];
    const float* sn2     = (const float*)d_in[12];
    const float* bias2   = (const float*)d_in[13];
    const float* fclr_w  = (const float*)d_in[14];
    const float* fclr_b  = (const float*)d_in[15];
    const float* convr_w = (const float*)d_in[16];
    const float* biasr   = (const float*)d_in[17];

    float* out_x2  = (float*)d_out;               // 16*64*64*512 fp32 = 128 MiB
    float* out_rgb = out_x2 + 33554432;           // 16*64*64*3 fp32 = 768 KiB

    // Scratch in the rgb tail (dead until torgb; torgb only WRITES there): 128 KiB.
    float* s1 = out_rgb;
    float* s2 = out_rgb + 8192;
    float* g1 = out_rgb + 16384;
    float* g2 = out_rgb + 24576;

    // preQ scratch in the t0 region (dead until conv1 writes t0; demod runs first)
    float* q1 = out_x2;              // 1 MiB
    float* q2 = out_x2 + 262144;     // 1 MiB

    // d_ws layout (63 MiB of the guaranteed 64):
    //   wb1  [0,       4.5Mi)  prepped conv1 weights (live until conv1 done)
    //   wb2  [4.5Mi,   9.0Mi)  prepped conv2 weights (live until conv2 done)
    //   xsp  [9.0Mi,  26.0Mi)  bf16 x*s1 haloed [16][33][33][512]
    //   x1b  [26.0Mi, 60.1Mi)  bf16 x1*s2 haloed [8][66][66][512], half-batch ping
    ushort_t* wb1 = (ushort_t*)d_ws;
    ushort_t* wb2 = wb1 + 2359296;                   // 9*16*512*32
    ushort_t* xsp = wb1 + 4718592;
    ushort_t* x1b = xsp + 8921088;                   // 16*33*33*512

    float* t0 = out_x2;  // pre-blur conv1 output (fp32), overwritten by x2 later

    const float WS33 = 0.014731391274719739f;     // 1/sqrt(9*512)

    style_fc_kernel<<<NB, 256, 0, stream>>>(w, fcl1_w, fcl1_b, s1);
    style_fc_kernel<<<NB, 256, 0, stream>>>(w, fcl2_w, fcl2_b, s2);
    wprep_kernel<<<dim3(8, 16), 256, 0, stream>>>(conv1_w, wb1, q1);
    wprep_kernel<<<dim3(8, 16), 256, 0, stream>>>(conv2_w, wb2, q2);
    demod2_kernel<<<dim3(2, NB), 256, 0, stream>>>(s1, q1, g1, WS33);
    demod2_kernel<<<dim3(2, NB), 256, 0, stream>>>(s2, q2, g2, WS33);
    xprep_kernel<<<dim3(33, 33, NB), 128, 0, stream>>>(x, s1, xsp);
    zero_kernel<<<8713, 256, 0, stream>>>((int4*)x1b, 2230272);   // 8*66*66*512*2B /16

    conv_mfma<1><<<dim3(4, 32, NB), 256, 0, stream>>>(
        xsp, wb1, g1, nullptr, nullptr, nullptr, t0, 0);

    for (int half = 0; half < 2; ++half) {
        // blur(half) consumes t0[b in half] before conv2(half) overwrites that region
        blur_kernel<<<dim3(WO, HO, 8), 128, 0, stream>>>(
            t0, noise1, sn1, bias1, s2, x1b, half * 8);
        conv_mfma<2><<<dim3(4, 32, 8), 256, 0, stream>>>(
            x1b, wb2, g2, noise2, sn2, bias2, out_x2, half * 8);
    }

    torgb_kernel<<<dim3(16, NB), 256, 0, stream>>>(out_x2, w, fclr_w, fclr_b, convr_w, biasr, out_rgb);
}

// Round 5
// 758.747 us; speedup vs baseline: 12.4621x; 1.2347x over previous
//
#include <hip/hip_runtime.h>
#include <hip/hip_bf16.h>

typedef __hip_bfloat16 bf16;
typedef __attribute__((ext_vector_type(8))) __bf16 bf16x8;
typedef __attribute__((ext_vector_type(4))) float f32x4;
typedef unsigned short ushort_t;

#define NB   16
#define HIN  32
#define WIN_ 32
#define C    512
#define HO   64
#define WO   64

__device__ __forceinline__ float lrelu(float v) { return v > 0.f ? v : 0.2f * v; }
__device__ __forceinline__ unsigned short f2bu(float f) {
    union { __hip_bfloat16 h; unsigned short u; } cv;
    cv.h = __float2bfloat16(f);
    return cv.u;
}
// async global->LDS, 16B per lane; lds base must be wave-uniform (lane writes +lane*16B)
__device__ __forceinline__ void gload16(const ushort_t* g, ushort_t* l) {
    __builtin_amdgcn_global_load_lds(
        (const __attribute__((address_space(1))) void*)g,
        (__attribute__((address_space(3))) void*)l, 16, 0, 0);
}

// All three equalized-lr FCs in one launch. blockIdx.y: 0->s1, 1->s2, 2->srgb.
__global__ __launch_bounds__(256) void style3_kernel(
    const float* __restrict__ w,
    const float* __restrict__ fw1, const float* __restrict__ fb1,
    const float* __restrict__ fw2, const float* __restrict__ fb2,
    const float* __restrict__ fwr, const float* __restrict__ fbr,
    float* __restrict__ s1, float* __restrict__ s2, float* __restrict__ srgb)
{
    const int b = blockIdx.x;
    const int which = blockIdx.y;
    const float* fw = which == 0 ? fw1 : (which == 1 ? fw2 : fwr);
    const float* fb = which == 0 ? fb1 : (which == 1 ? fb2 : fbr);
    float* dst      = which == 0 ? s1  : (which == 1 ? s2  : srgb);
    __shared__ float wrow[C];
    for (int i = threadIdx.x; i < C; i += 256) wrow[i] = w[b * C + i];
    __syncthreads();
    const float scale = 0.044194173824159216f;  // 1/sqrt(512)
    for (int co = threadIdx.x; co < C; co += 256) {
        float acc = 0.f;
        for (int ci = 0; ci < C; ci++)
            acc = fmaf(wrow[ci], fw[ci * C + co], acc);
        dst[b * C + co] = acc * scale + fb[co];
    }
}

// One pass over a weight tensor: emit (a) bf16 transposed layout
// wb[t][ct][n=co][kk=ci&31] ready for global_load_lds staging, (b) q[ci][co]=sum_t w^2.
// blockIdx.z selects conv1 / conv2 tensor.
__global__ __launch_bounds__(256) void wprep2_kernel(
    const float* __restrict__ cw1, const float* __restrict__ cw2,
    ushort_t* __restrict__ wb1, ushort_t* __restrict__ wb2,
    float* __restrict__ q1, float* __restrict__ q2)
{
    const float* cw = blockIdx.z == 0 ? cw1 : cw2;
    ushort_t* wb    = blockIdx.z == 0 ? wb1 : wb2;
    float* q        = blockIdx.z == 0 ? q1  : q2;
    const int nc = blockIdx.x;   // co block of 64
    const int ct = blockIdx.y;   // ci block of 32
    const int tid = threadIdx.x;
    __shared__ float tile[32][65];
    float qacc[8];
    #pragma unroll
    for (int p = 0; p < 8; ++p) qacc[p] = 0.f;
    const int rr = tid >> 6;        // 0..3 (read row within pass)
    const int cc = tid & 63;        // 0..63 (read col)
    const int n  = tid >> 2;        // 0..63 (write col)
    const int kq = tid & 3;         // write kk quad -> kk = kq*8..+7
    for (int t = 0; t < 9; ++t) {
        #pragma unroll
        for (int p = 0; p < 8; ++p) {
            const int r = p * 4 + rr;
            float v = cw[((size_t)(t * C + ct * 32 + r)) * C + nc * 64 + cc];
            tile[r][cc] = v;
            qacc[p] = fmaf(v, v, qacc[p]);
        }
        __syncthreads();
        unsigned int d[4];
        #pragma unroll
        for (int j2 = 0; j2 < 4; ++j2)
            d[j2] = (unsigned int)f2bu(tile[kq * 8 + 2 * j2][n])
                  | ((unsigned int)f2bu(tile[kq * 8 + 2 * j2 + 1][n]) << 16);
        int4 w4 = { (int)d[0], (int)d[1], (int)d[2], (int)d[3] };
        *(int4*)&wb[(((size_t)t * 16 + ct) * 512 + nc * 64 + n) * 32 + kq * 8] = w4;
        __syncthreads();
    }
    #pragma unroll
    for (int p = 0; p < 8; ++p)
        q[(ct * 32 + p * 4 + rr) * C + nc * 64 + cc] = qacc[p];
}

// g[b,co] = wscale * rsqrt(wscale^2 * sum_ci q[ci][co]*s^2[b][ci] + 1e-8); z selects set.
__global__ __launch_bounds__(256) void demod3_kernel(
    const float* __restrict__ s1, const float* __restrict__ s2,
    const float* __restrict__ q1, const float* __restrict__ q2,
    float* __restrict__ g1, float* __restrict__ g2, float wscale)
{
    const float* s = blockIdx.z == 0 ? s1 : s2;
    const float* q = blockIdx.z == 0 ? q1 : q2;
    float* g       = blockIdx.z == 0 ? g1 : g2;
    const int b = blockIdx.y;
    const int co = blockIdx.x * 256 + threadIdx.x;
    __shared__ float sq[C];
    for (int i = threadIdx.x; i < C; i += 256) {
        float v = s[b * C + i];
        sq[i] = v * v;
    }
    __syncthreads();
    float acc = 0.f;
    for (int ci = 0; ci < C; ++ci)
        acc = fmaf(q[ci * C + co], sq[ci], acc);
    g[b * C + co] = wscale / sqrtf(acc * wscale * wscale + 1e-8f);
}

// x*s1 -> bf16, padded [16][33][33][512] with zero halo at iy=0 / ix=0
__global__ __launch_bounds__(128) void xprep_kernel(
    const float* __restrict__ x, const float* __restrict__ s1,
    ushort_t* __restrict__ xp)
{
    const int ix = blockIdx.x;   // 0..32
    const int iy = blockIdx.y;   // 0..32
    const int b  = blockIdx.z;
    const int c  = threadIdx.x * 4;
    int2 pk{0, 0};
    if (iy > 0 && ix > 0) {
        const float4 xv = *(const float4*)&x[(((size_t)b * HIN + iy - 1) * WIN_ + ix - 1) * C + c];
        const float4 sv = *(const float4*)&s1[b * C + c];
        pk.x = (int)f2bu(xv.x * sv.x) | ((int)f2bu(xv.y * sv.y) << 16);
        pk.y = (int)f2bu(xv.z * sv.z) | ((int)f2bu(xv.w * sv.w) << 16);
    }
    *(int2*)&xp[(((size_t)b * 33 + iy) * 33 + ix) * 512 + c] = pk;
}

__global__ __launch_bounds__(256) void zero_kernel(int4* __restrict__ p, int n16)
{
    int i = blockIdx.x * 256 + threadIdx.x;
    int4 z{0, 0, 0, 0};
    if (i < n16) p[i] = z;
}

// Implicit-GEMM MFMA conv. Tile M=256 x N=128 x BK=32; 4 waves 2x2; each wave
// owns 128x64 via 8x4 frags of mfma 16x16x32 (32 MFMA / 12 ds_read_b128 per
// step = 2.67 ratio vs 2.0 before -> higher LDS arithmetic intensity).
// 3-slot LDS ring, prefetch distance 2, counted vmcnt (T3+T4). Per step:
//   [vmcnt(6); s_barrier; ds_read frags(buf it); issue stage(it+2); setprio(1);
//    32 MFMA; setprio(0)].
// Race-safety of the 3-slot ring: readers of slot (it-1)%3 completed their LDS
// reads before reaching barrier(it) (MFMA consumption forces lgkm drain); the
// stage(it+2) DMA targeting that same slot is issued only after barrier(it).
// vmcnt(6) before barrier(it) leaves only stage(it+1)'s 6 loads in flight ->
// buf[it] guaranteed landed. Tail: vmcnt(0) on the last step.
// MODE 1: transposed 3x3 s2 conv as parity classes (gy = cl*4 + iblock);
//   input = prepped bf16 x*s1 halo [16][33][33][512]; out = t0 fp32, epilogue *g.
// MODE 2: 3x3 s1 conv; input = haloed bf16 x1*s2 [8][66][66][512]; epilogue
//   *g + noise + bias + lrelu.
// LDS granule swizzle slot q^((m>>1)&3) via pre-swizzled global source (rule #21);
// read addr uses lg^((ln15>>1)&3) -> conflict-free ds_read_b128 (verified R3: 0).
// Grid id XCD-swizzled (bijective, nwg%8==0).
template<int MODE>
__global__ __launch_bounds__(256, 2) void conv_mfma(
    const ushort_t* __restrict__ xin, const ushort_t* __restrict__ wb,
    const float* __restrict__ g,
    const float* __restrict__ noise, const float* __restrict__ sn,
    const float* __restrict__ bias, float* __restrict__ out, int b0)
{
    // ---- XCD-aware bijective block swizzle (T1): nwg = 4*16*gridZ, %8 == 0 ----
    const int id  = blockIdx.x + 4 * (blockIdx.y + 16 * blockIdx.z);
    const int cpx = 8 * gridDim.z;                // nwg/8
    const int nid = (id & 7) * cpx + (id >> 3);
    const int n0 = (nid & 3) * 128;
    const int gy = (nid >> 2) & 15;
    const int bz = nid >> 6;
    const int b  = b0 + bz;

    const int tid = threadIdx.x;
    const int lane = tid & 63, wave = tid >> 6;
    const int wr = wave >> 1, wc = wave & 1;
    const int ln15 = lane & 15, lg = lane >> 4;

    __shared__ ushort_t As[3][8192];   // 256 rows x 32 k
    __shared__ ushort_t Bs[3][4096];   // 128 rows x 32 k
    __shared__ float nzs[256];

    int ntap = 9;
    int i0 = 0, cla = 0, clc = 0, oyb = 0, nkx = 1;
    if constexpr (MODE == 1) {
        const int cl = gy >> 2;        // parity class 0..3
        i0 = (gy & 3) * 8;             // 8 input rows per tile
        cla = cl >> 1; clc = cl & 1;
        const int nky = (cla == 0) ? 2 : 1;
        nkx = (clc == 0) ? 2 : 1;
        ntap = nky * nkx;
    } else {
        oyb = gy;                      // 4 output rows per tile
        nzs[tid] = noise[(b * HO + oyb * 4 + (tid >> 6)) * WO + (tid & 63)];
    }

    // per-thread global bases (element units), granule-swizzled: qs = (s&3)^((s>>3)&3)
    int abase[4], bbase[2];
    #pragma unroll
    for (int j = 0; j < 4; ++j) {
        const int s = tid + 256 * j;
        const int m = s >> 2;
        const int qs = (s & 3) ^ ((s >> 3) & 3);
        if constexpr (MODE == 2) {
            abase[j] = ((bz * 66 + oyb * 4 + (m >> 6)) * 66 + (m & 63)) * 512 + qs * 8;
        } else {
            abase[j] = ((b * 33 + i0 + (m >> 5) + 1) * 33 + (m & 31) + 1) * 512 + qs * 8;
        }
    }
    #pragma unroll
    for (int j = 0; j < 2; ++j) {
        const int s = tid + 256 * j;
        const int qs = (s & 3) ^ ((s >> 3) & 3);
        bbase[j] = n0 * 32 + (s >> 2) * 32 + qs * 8;
    }

    auto issue = [&](int sl, int ao, int bo) {
        #pragma unroll
        for (int j = 0; j < 4; ++j)
            gload16(xin + abase[j] + ao, &As[sl][wave * 512 + j * 2048]);
        #pragma unroll
        for (int j = 0; j < 2; ++j)
            gload16(wb + bo + bbase[j], &Bs[sl][wave * 512 + j * 2048]);
    };

    // tap offset helper (wave-uniform SALU; runs once per 16 steps)
    auto tap1 = [&](int u, int v, int& ao, int& bo) {
        const int ky = (cla == 0) ? 2 * u : 1;
        const int kx = (clc == 0) ? 2 * v : 1;
        const int dy = (cla + ky - 2) >> 1, dx = (clc + kx - 2) >> 1;
        ao = (dy * 33 + dx) * 512;
        bo = (ky * 3 + kx) * 262144;
    };

    // hoisted, loop-invariant fragment LDS addresses (element units)
    const int fs = (lg ^ ((ln15 >> 1) & 3)) * 8;
    int ra[8], rb[4];
    #pragma unroll
    for (int i = 0; i < 8; ++i) ra[i] = (wr * 128 + i * 16 + ln15) * 32 + fs;
    #pragma unroll
    for (int i = 0; i < 4; ++i) rb[i] = (wc * 64 + i * 16 + ln15) * 32 + fs;

    f32x4 acc[8][4];
    #pragma unroll
    for (int i = 0; i < 8; ++i)
        #pragma unroll
        for (int j = 0; j < 4; ++j) {
            f32x4 z = {0.f, 0.f, 0.f, 0.f};
            acc[i][j] = z;
        }

    // stage-side state (wave-uniform), tracks the NEXT stage to issue
    int s_ci = 0, s_u = 0, s_v = 0, s_ky = 0, s_kx = 0;
    int s_ao, s_bo;
    if constexpr (MODE == 1) tap1(0, 0, s_ao, s_bo);
    else { s_ao = 0; s_bo = 0; }

    auto advance = [&]() {
        ++s_ci;
        s_ao += 32; s_bo += 16384;
        if (s_ci == 16) {
            s_ci = 0;
            if constexpr (MODE == 1) {
                if (++s_v == nkx) { s_v = 0; ++s_u; }
                tap1(s_u, s_v, s_ao, s_bo);
            } else {
                if (++s_kx == 3) { s_kx = 0; ++s_ky; }
                s_ao = (s_ky * 66 + s_kx) * 512;
                s_bo = (s_ky * 3 + s_kx) * 262144;
            }
        }
    };

    const int nstep = ntap * 16;   // always >= 16
    issue(0, s_ao, s_bo); advance();
    issue(1, s_ao, s_bo); advance();

    int sl = 0, slp = 2;           // slot of buf[it] / of stage(it+2)
    for (int it = 0; it < nstep; ++it) {
        if (it + 1 < nstep) asm volatile("s_waitcnt vmcnt(6)" ::: "memory");
        else                asm volatile("s_waitcnt vmcnt(0)" ::: "memory");
        __builtin_amdgcn_s_barrier();
        __builtin_amdgcn_sched_barrier(0);

        const ushort_t* __restrict__ curA = As[sl];
        const ushort_t* __restrict__ curB = Bs[sl];
        bf16x8 aF[8], bF[4];
        #pragma unroll
        for (int mi = 0; mi < 8; ++mi)
            aF[mi] = *(const bf16x8*)&curA[ra[mi]];
        #pragma unroll
        for (int ni = 0; ni < 4; ++ni)
            bF[ni] = *(const bf16x8*)&curB[rb[ni]];

        if (it + 2 < nstep) {
            issue(slp, s_ao, s_bo);
            advance();
        }

        __builtin_amdgcn_s_setprio(1);
        #pragma unroll
        for (int mi = 0; mi < 8; ++mi)
            #pragma unroll
            for (int ni = 0; ni < 4; ++ni)
                acc[mi][ni] = __builtin_amdgcn_mfma_f32_16x16x32_bf16(
                    aF[mi], bF[ni], acc[mi][ni], 0, 0, 0);
        __builtin_amdgcn_s_setprio(0);

        sl  = (sl == 2)  ? 0 : sl + 1;
        slp = (slp == 2) ? 0 : slp + 1;
    }

    // epilogue: D col = lane&15 (n), row = (lane>>4)*4 + reg (m)
    #pragma unroll
    for (int ni = 0; ni < 4; ++ni) {
        const int n = n0 + wc * 64 + ni * 16 + ln15;
        const float gv = g[b * C + n];
        float snv = 0.f, bv = 0.f;
        if constexpr (MODE == 2) { snv = sn[n]; bv = bias[n]; }
        #pragma unroll
        for (int mi = 0; mi < 8; ++mi) {
            #pragma unroll
            for (int j = 0; j < 4; ++j) {
                const int m = wr * 128 + mi * 16 + lg * 4 + j;
                int oy, ox;
                if constexpr (MODE == 1) { oy = 2 * (i0 + (m >> 5)) + cla; ox = 2 * (m & 31) + clc; }
                else { oy = oyb * 4 + (m >> 6); ox = m & 63; }
                const size_t idx = ((size_t)((b * HO + oy) * WO + ox) << 9) + n;
                float v = acc[mi][ni][j] * gv;
                if constexpr (MODE == 2) v = lrelu(v + snv * nzs[m] + bv);
                out[idx] = v;
            }
        }
    }
}

// 4x4 FIR blur + noise + bias + lrelu, then fold s2; bf16 into haloed x1buf [8][66][66][512]
__global__ __launch_bounds__(128) void blur_kernel(
    const float* __restrict__ t0, const float* __restrict__ noise1,
    const float* __restrict__ sn1, const float* __restrict__ bias1,
    const float* __restrict__ s2, ushort_t* __restrict__ x1, int b0)
{
    const int ox = blockIdx.x, oy = blockIdx.y, bq = blockIdx.z;
    const int b = b0 + bq;
    const float nz = noise1[(b * HO + oy) * WO + ox];
    const int c = threadIdx.x * 4;
    float a0 = 0.f, a1 = 0.f, a2 = 0.f, a3 = 0.f;
    const float F[4] = {1.f, 3.f, 3.f, 1.f};
    #pragma unroll
    for (int i = 0; i < 4; ++i) {
        int iy = oy + i - 1;
        if ((unsigned)iy >= (unsigned)HO) continue;
        #pragma unroll
        for (int j = 0; j < 4; ++j) {
            int ix = ox + j - 1;
            if ((unsigned)ix >= (unsigned)WO) continue;
            float wgt = F[i] * F[j];
            const float4 v = *(const float4*)&t0[((size_t)((b * HO + iy) * WO + ix) << 9) + c];
            a0 = fmaf(wgt, v.x, a0); a1 = fmaf(wgt, v.y, a1);
            a2 = fmaf(wgt, v.z, a2); a3 = fmaf(wgt, v.w, a3);
        }
    }
    const float4 sv = *(const float4*)&sn1[c];
    const float4 bv = *(const float4*)&bias1[c];
    const float4 s2v = *(const float4*)&s2[b * C + c];
    a0 = lrelu(fmaf(sv.x, nz, a0 * 0.0625f) + bv.x) * s2v.x;
    a1 = lrelu(fmaf(sv.y, nz, a1 * 0.0625f) + bv.y) * s2v.y;
    a2 = lrelu(fmaf(sv.z, nz, a2 * 0.0625f) + bv.z) * s2v.z;
    a3 = lrelu(fmaf(sv.w, nz, a3 * 0.0625f) + bv.w) * s2v.w;
    int2 pk;
    pk.x = (int)f2bu(a0) | ((int)f2bu(a1) << 16);
    pk.y = (int)f2bu(a2) | ((int)f2bu(a3) << 16);
    *(int2*)&x1[(((size_t)bq * 66 + oy + 1) * 66 + ox + 1) * 512 + c] = pk;
}

// 1x1 conv (no demod) + bias + lrelu -> rgb. Coalesced: 16 px x 16 lanes per
// block, 256B contiguous segments per 16-lane group, shfl_xor width-16 reduce.
// Style comes from precomputed srgb (scratch lives in d_ws, NOT in the rgb region).
__global__ __launch_bounds__(256) void torgb2_kernel(
    const float* __restrict__ x2, const float* __restrict__ srgb,
    const float* __restrict__ wr, const float* __restrict__ biasr,
    float* __restrict__ rgb)
{
    const int b = blockIdx.y;
    const int tid = threadIdx.x;
    __shared__ float weff[C][3];
    const float scale = 0.044194173824159216f;  // 1/sqrt(512) conv wscale
    for (int ci = tid; ci < C; ci += 256) {
        float sc = scale * srgb[b * C + ci];
        weff[ci][0] = sc * wr[ci * 3 + 0];
        weff[ci][1] = sc * wr[ci * 3 + 1];
        weff[ci][2] = sc * wr[ci * 3 + 2];
    }
    __syncthreads();
    const int l16 = tid & 15;
    const int px  = blockIdx.x * 16 + (tid >> 4);
    const float* base = x2 + ((size_t)(b * 4096 + px) << 9);
    float a0 = 0.f, a1 = 0.f, a2 = 0.f;
    #pragma unroll
    for (int i = 0; i < 8; ++i) {
        const int c = i * 64 + l16 * 4;
        const float4 v = *(const float4*)&base[c];
        a0 = fmaf(v.x, weff[c][0], a0);     a1 = fmaf(v.x, weff[c][1], a1);     a2 = fmaf(v.x, weff[c][2], a2);
        a0 = fmaf(v.y, weff[c+1][0], a0);   a1 = fmaf(v.y, weff[c+1][1], a1);   a2 = fmaf(v.y, weff[c+1][2], a2);
        a0 = fmaf(v.z, weff[c+2][0], a0);   a1 = fmaf(v.z, weff[c+2][1], a1);   a2 = fmaf(v.z, weff[c+2][2], a2);
        a0 = fmaf(v.w, weff[c+3][0], a0);   a1 = fmaf(v.w, weff[c+3][1], a1);   a2 = fmaf(v.w, weff[c+3][2], a2);
    }
    #pragma unroll
    for (int off = 1; off < 16; off <<= 1) {
        a0 += __shfl_xor(a0, off, 16);
        a1 += __shfl_xor(a1, off, 16);
        a2 += __shfl_xor(a2, off, 16);
    }
    if (l16 < 3) {
        float v = l16 == 0 ? a0 : (l16 == 1 ? a1 : a2);
        rgb[(size_t)(b * 4096 + px) * 3 + l16] = lrelu(v + biasr[l16]);
    }
}

extern "C" void kernel_launch(void* const* d_in, const int* in_sizes, int n_in,
                              void* d_out, int out_size, void* d_ws, size_t ws_size,
                              hipStream_t stream)
{
    (void)in_sizes; (void)n_in; (void)out_size; (void)ws_size;
    const float* x       = (const float*)d_in[0];
    const float* w       = (const float*)d_in[1];
    const float* noise1  = (const float*)d_in[2];
    const float* noise2  = (const float*)d_in[3];
    const float* fcl1_w  = (const float*)d_in[4];
    const float* fcl1_b  = (const float*)d_in[5];
    const float* conv1_w = (const float*)d_in[6];
    const float* sn1     = (const float*)d_in[7];
    const float* bias1   = (const float*)d_in[8];
    const float* fcl2_w  = (const float*)d_in[9];
    const float* fcl2_b  = (const float*)d_in[10];
    const float* conv2_w = (const float*)d_in[11];
    const float* sn2     = (const float*)d_in[12];
    const float* bias2   = (const float*)d_in[13];
    const float* fclr_w  = (const float*)d_in[14];
    const float* fclr_b  = (const float*)d_in[15];
    const float* convr_w = (const float*)d_in[16];
    const float* biasr   = (const float*)d_in[17];

    float* out_x2  = (float*)d_out;               // 16*64*64*512 fp32 = 128 MiB
    float* out_rgb = out_x2 + 33554432;           // 16*64*64*3 fp32 = 768 KiB (pure output now)

    // d_ws layout (~62.2 MiB of the guaranteed 64):
    //   wb1  [0,       4.5Mi)  prepped conv1 weights
    //   wb2  [4.5Mi,   9.0Mi)  prepped conv2 weights
    //   xsp  [9.0Mi,  26.0Mi)  bf16 x*s1 haloed [16][33][33][512]
    //   x1b  [26.0Mi, 60.05Mi) bf16 x1*s2 haloed [8][66][66][512], half-batch ping
    //   scr  [60.05Mi, ...]    s1,s2,g1,g2,srgb (8K floats each) + q1,q2 (256K each)
    ushort_t* wb1 = (ushort_t*)d_ws;
    ushort_t* wb2 = wb1 + 2359296;                   // 9*16*512*32
    ushort_t* xsp = wb1 + 4718592;
    ushort_t* x1b = xsp + 8921088;                   // 16*33*33*512
    float* scr = (float*)(x1b + 17842176);           // 8*66*66*512
    float* s1   = scr;
    float* s2   = scr + 8192;
    float* g1   = scr + 16384;
    float* g2   = scr + 24576;
    float* srgb = scr + 32768;
    float* q1   = scr + 40960;
    float* q2   = scr + 303104;

    float* t0 = out_x2;  // pre-blur conv1 output (fp32), overwritten by x2 later

    const float WS33 = 0.014731391274719739f;     // 1/sqrt(9*512)

    style3_kernel<<<dim3(NB, 3), 256, 0, stream>>>(
        w, fcl1_w, fcl1_b, fcl2_w, fcl2_b, fclr_w, fclr_b, s1, s2, srgb);
    wprep2_kernel<<<dim3(8, 16, 2), 256, 0, stream>>>(conv1_w, conv2_w, wb1, wb2, q1, q2);
    demod3_kernel<<<dim3(2, NB, 2), 256, 0, stream>>>(s1, s2, q1, q2, g1, g2, WS33);
    xprep_kernel<<<dim3(33, 33, NB), 128, 0, stream>>>(x, s1, xsp);
    zero_kernel<<<8713, 256, 0, stream>>>((int4*)x1b, 2230272);   // 8*66*66*512*2B /16

    conv_mfma<1><<<dim3(4, 16, NB), 256, 0, stream>>>(
        xsp, wb1, g1, nullptr, nullptr, nullptr, t0, 0);

    for (int half = 0; half < 2; ++half) {
        // blur(half) consumes t0[b in half] before conv2(half) overwrites that region
        blur_kernel<<<dim3(WO, HO, 8), 128, 0, stream>>>(
            t0, noise1, sn1, bias1, s2, x1b, half * 8);
        conv_mfma<2><<<dim3(4, 16, 8), 256, 0, stream>>>(
            x1b, wb2, g2, noise2, sn2, bias2, out_x2, half * 8);
    }

    torgb2_kernel<<<dim3(256, NB), 256, 0, stream>>>(out_x2, srgb, convr_w, biasr, out_rgb);
}

// Round 7
// 678.681 us; speedup vs baseline: 13.9323x; 1.1180x over previous
//
#include <hip/hip_runtime.h>
#include <hip/hip_bf16.h>

typedef __hip_bfloat16 bf16;
typedef __attribute__((ext_vector_type(8))) __bf16 bf16x8;
typedef __attribute__((ext_vector_type(4))) float f32x4;
typedef unsigned short ushort_t;

#define NB   16
#define HIN  32
#define WIN_ 32
#define C    512
#define HO   64
#define WO   64

__device__ __forceinline__ float lrelu(float v) { return v > 0.f ? v : 0.2f * v; }
__device__ __forceinline__ unsigned short f2bu(float f) {
    union { __hip_bfloat16 h; unsigned short u; } cv;
    cv.h = __float2bfloat16(f);
    return cv.u;
}
// async global->LDS, 16B per lane; lds base must be wave-uniform (lane writes +lane*16B)
__device__ __forceinline__ void gload16(const ushort_t* g, ushort_t* l) {
    __builtin_amdgcn_global_load_lds(
        (const __attribute__((address_space(1))) void*)g,
        (__attribute__((address_space(3))) void*)l, 16, 0, 0);
}

// All three equalized-lr FCs in one launch. blockIdx.y: 0->s1, 1->s2, 2->srgb.
__global__ __launch_bounds__(256) void style3_kernel(
    const float* __restrict__ w,
    const float* __restrict__ fw1, const float* __restrict__ fb1,
    const float* __restrict__ fw2, const float* __restrict__ fb2,
    const float* __restrict__ fwr, const float* __restrict__ fbr,
    float* __restrict__ s1, float* __restrict__ s2, float* __restrict__ srgb)
{
    const int b = blockIdx.x;
    const int which = blockIdx.y;
    const float* fw = which == 0 ? fw1 : (which == 1 ? fw2 : fwr);
    const float* fb = which == 0 ? fb1 : (which == 1 ? fb2 : fbr);
    float* dst      = which == 0 ? s1  : (which == 1 ? s2  : srgb);
    __shared__ float wrow[C];
    for (int i = threadIdx.x; i < C; i += 256) wrow[i] = w[b * C + i];
    __syncthreads();
    const float scale = 0.044194173824159216f;  // 1/sqrt(512)
    for (int co = threadIdx.x; co < C; co += 256) {
        float acc = 0.f;
        for (int ci = 0; ci < C; ci++)
            acc = fmaf(wrow[ci], fw[ci * C + co], acc);
        dst[b * C + co] = acc * scale + fb[co];
    }
}

// One pass over a weight tensor: emit (a) bf16 transposed layout
// wb[t][ct][n=co][kk=ci&31] ready for global_load_lds staging, (b) q[ci][co]=sum_t w^2.
// blockIdx.z selects conv1 / conv2 tensor.
__global__ __launch_bounds__(256) void wprep2_kernel(
    const float* __restrict__ cw1, const float* __restrict__ cw2,
    ushort_t* __restrict__ wb1, ushort_t* __restrict__ wb2,
    float* __restrict__ q1, float* __restrict__ q2)
{
    const float* cw = blockIdx.z == 0 ? cw1 : cw2;
    ushort_t* wb    = blockIdx.z == 0 ? wb1 : wb2;
    float* q        = blockIdx.z == 0 ? q1  : q2;
    const int nc = blockIdx.x;   // co block of 64
    const int ct = blockIdx.y;   // ci block of 32
    const int tid = threadIdx.x;
    __shared__ float tile[32][65];
    float qacc[8];
    #pragma unroll
    for (int p = 0; p < 8; ++p) qacc[p] = 0.f;
    const int rr = tid >> 6;        // 0..3 (read row within pass)
    const int cc = tid & 63;        // 0..63 (read col)
    const int n  = tid >> 2;        // 0..63 (write col)
    const int kq = tid & 3;         // write kk quad -> kk = kq*8..+7
    for (int t = 0; t < 9; ++t) {
        #pragma unroll
        for (int p = 0; p < 8; ++p) {
            const int r = p * 4 + rr;
            float v = cw[((size_t)(t * C + ct * 32 + r)) * C + nc * 64 + cc];
            tile[r][cc] = v;
            qacc[p] = fmaf(v, v, qacc[p]);
        }
        __syncthreads();
        unsigned int d[4];
        #pragma unroll
        for (int j2 = 0; j2 < 4; ++j2)
            d[j2] = (unsigned int)f2bu(tile[kq * 8 + 2 * j2][n])
                  | ((unsigned int)f2bu(tile[kq * 8 + 2 * j2 + 1][n]) << 16);
        int4 w4 = { (int)d[0], (int)d[1], (int)d[2], (int)d[3] };
        *(int4*)&wb[(((size_t)t * 16 + ct) * 512 + nc * 64 + n) * 32 + kq * 8] = w4;
        __syncthreads();
    }
    #pragma unroll
    for (int p = 0; p < 8; ++p)
        q[(ct * 32 + p * 4 + rr) * C + nc * 64 + cc] = qacc[p];
}

// g[b,co] = wscale * rsqrt(wscale^2 * sum_ci q[ci][co]*s^2[b][ci] + 1e-8); z selects set.
__global__ __launch_bounds__(256) void demod3_kernel(
    const float* __restrict__ s1, const float* __restrict__ s2,
    const float* __restrict__ q1, const float* __restrict__ q2,
    float* __restrict__ g1, float* __restrict__ g2, float wscale)
{
    const float* s = blockIdx.z == 0 ? s1 : s2;
    const float* q = blockIdx.z == 0 ? q1 : q2;
    float* g       = blockIdx.z == 0 ? g1 : g2;
    const int b = blockIdx.y;
    const int co = blockIdx.x * 256 + threadIdx.x;
    __shared__ float sq[C];
    for (int i = threadIdx.x; i < C; i += 256) {
        float v = s[b * C + i];
        sq[i] = v * v;
    }
    __syncthreads();
    float acc = 0.f;
    for (int ci = 0; ci < C; ++ci)
        acc = fmaf(q[ci * C + co], sq[ci], acc);
    g[b * C + co] = wscale / sqrtf(acc * wscale * wscale + 1e-8f);
}

// x*s1 -> bf16, padded [16][33][33][512] with zero halo at iy=0 / ix=0. Flat grid.
__global__ __launch_bounds__(256) void xprep_kernel(
    const float* __restrict__ x, const float* __restrict__ s1,
    ushort_t* __restrict__ xp)
{
    const int u = blockIdx.x * 256 + threadIdx.x;   // int2 units of 4 ch
    if (u >= 16 * 1089 * 128) return;
    const int c4 = (u & 127) * 4;
    const int p  = u >> 7;                // 0..17423 = [b][iy][ix]
    const int b  = p / 1089;
    const int r  = p - b * 1089;
    const int iy = r / 33;
    const int ix = r - iy * 33;
    int2 pk{0, 0};
    if (iy > 0 && ix > 0) {
        const float4 xv = *(const float4*)&x[(((size_t)b * HIN + iy - 1) * WIN_ + ix - 1) * C + c4];
        const float4 sv = *(const float4*)&s1[b * C + c4];
        pk.x = (int)f2bu(xv.x * sv.x) | ((int)f2bu(xv.y * sv.y) << 16);
        pk.y = (int)f2bu(xv.z * sv.z) | ((int)f2bu(xv.w * sv.w) << 16);
    }
    *(int2*)&xp[(size_t)p * 512 + c4] = pk;
}

// Zero only the halo frame of x1b [8][66][66][512] (interior is fully written by blur).
__global__ __launch_bounds__(256) void zero_halo_kernel(ushort_t* __restrict__ x1)
{
    const int u = blockIdx.x * 256 + threadIdx.x;   // int4 units of 8 ch
    if (u >= 8 * 260 * 64) return;
    const int bq = u / 16640;
    const int r  = u - bq * 16640;
    const int pi = r >> 6;          // 0..259 halo px index
    const int cq = (r & 63) * 8;
    int yy, xx;
    if (pi < 66)       { yy = 0;        xx = pi; }
    else if (pi < 132) { yy = 65;       xx = pi - 66; }
    else if (pi < 196) { yy = pi - 131; xx = 0;  }     // rows 1..64
    else               { yy = pi - 195; xx = 65; }     // rows 1..64
    int4 z{0, 0, 0, 0};
    *(int4*)&x1[(((size_t)bq * 66 + yy) * 66 + xx) * 512 + cq] = z;
}

// Implicit-GEMM MFMA conv. Tile M=256 x N=128 x BK=32; 4 waves 2x2; each wave
// owns 128x64 via 8x4 frags of mfma 16x16x32 (32 MFMA / 12 ds_read_b128/step).
// 3-slot LDS ring, prefetch distance 2, counted vmcnt (T3+T4). Per step:
//   [vmcnt(6); s_barrier; ds_read frags(buf it); issue stage(it+2); setprio(1);
//    32 MFMA; setprio(0)].  (race-safety argument unchanged from R4/R5)
// MODE 1: transposed 3x3 s2 conv as parity classes; input = bf16 x*s1 halo
//   [16][33][33][512]; out = t0 BF16 (ushort), epilogue *g.
// MODE 2: 3x3 s1 conv; input = haloed bf16 x1*s2 [8][66][66][512]; epilogue
//   *g + noise + bias + lrelu -> fp32 x2.
// LDS granule swizzle slot q^((m>>1)&3) via pre-swizzled global source (rule #21);
// read addr uses lg^((ln15>>1)&3) -> conflict-free (verified: SQ_LDS_BANK_CONFLICT=0).
// Grid id XCD-swizzled (bijective, nwg%8==0).
template<int MODE>
__global__ __launch_bounds__(256, 2) void conv_mfma(
    const ushort_t* __restrict__ xin, const ushort_t* __restrict__ wb,
    const float* __restrict__ g,
    const float* __restrict__ noise, const float* __restrict__ sn,
    const float* __restrict__ bias, float* __restrict__ out, int b0)
{
    // ---- XCD-aware bijective block swizzle (T1): nwg = 4*16*gridZ, %8 == 0 ----
    const int id  = blockIdx.x + 4 * (blockIdx.y + 16 * blockIdx.z);
    const int cpx = 8 * gridDim.z;                // nwg/8
    const int nid = (id & 7) * cpx + (id >> 3);
    const int n0 = (nid & 3) * 128;
    const int gy = (nid >> 2) & 15;
    const int bz = nid >> 6;
    const int b  = b0 + bz;

    const int tid = threadIdx.x;
    const int lane = tid & 63, wave = tid >> 6;
    const int wr = wave >> 1, wc = wave & 1;
    const int ln15 = lane & 15, lg = lane >> 4;

    __shared__ ushort_t As[3][8192];   // 256 rows x 32 k
    __shared__ ushort_t Bs[3][4096];   // 128 rows x 32 k
    __shared__ float nzs[256];

    int ntap = 9;
    int i0 = 0, cla = 0, clc = 0, oyb = 0, nkx = 1;
    if constexpr (MODE == 1) {
        const int cl = gy >> 2;        // parity class 0..3
        i0 = (gy & 3) * 8;             // 8 input rows per tile
        cla = cl >> 1; clc = cl & 1;
        const int nky = (cla == 0) ? 2 : 1;
        nkx = (clc == 0) ? 2 : 1;
        ntap = nky * nkx;
    } else {
        oyb = gy;                      // 4 output rows per tile
        nzs[tid] = noise[(b * HO + oyb * 4 + (tid >> 6)) * WO + (tid & 63)];
    }

    // per-thread global bases (element units), granule-swizzled: qs = (s&3)^((s>>3)&3)
    int abase[4], bbase[2];
    #pragma unroll
    for (int j = 0; j < 4; ++j) {
        const int s = tid + 256 * j;
        const int m = s >> 2;
        const int qs = (s & 3) ^ ((s >> 3) & 3);
        if constexpr (MODE == 2) {
            abase[j] = ((bz * 66 + oyb * 4 + (m >> 6)) * 66 + (m & 63)) * 512 + qs * 8;
        } else {
            abase[j] = ((b * 33 + i0 + (m >> 5) + 1) * 33 + (m & 31) + 1) * 512 + qs * 8;
        }
    }
    #pragma unroll
    for (int j = 0; j < 2; ++j) {
        const int s = tid + 256 * j;
        const int qs = (s & 3) ^ ((s >> 3) & 3);
        bbase[j] = n0 * 32 + (s >> 2) * 32 + qs * 8;
    }

    auto issue = [&](int sl, int ao, int bo) {
        #pragma unroll
        for (int j = 0; j < 4; ++j)
            gload16(xin + abase[j] + ao, &As[sl][wave * 512 + j * 2048]);
        #pragma unroll
        for (int j = 0; j < 2; ++j)
            gload16(wb + bo + bbase[j], &Bs[sl][wave * 512 + j * 2048]);
    };

    // tap offset helper (wave-uniform SALU; runs once per 16 steps)
    auto tap1 = [&](int u, int v, int& ao, int& bo) {
        const int ky = (cla == 0) ? 2 * u : 1;
        const int kx = (clc == 0) ? 2 * v : 1;
        const int dy = (cla + ky - 2) >> 1, dx = (clc + kx - 2) >> 1;
        ao = (dy * 33 + dx) * 512;
        bo = (ky * 3 + kx) * 262144;
    };

    // hoisted, loop-invariant fragment LDS addresses (element units)
    const int fs = (lg ^ ((ln15 >> 1) & 3)) * 8;
    int ra[8], rb[4];
    #pragma unroll
    for (int i = 0; i < 8; ++i) ra[i] = (wr * 128 + i * 16 + ln15) * 32 + fs;
    #pragma unroll
    for (int i = 0; i < 4; ++i) rb[i] = (wc * 64 + i * 16 + ln15) * 32 + fs;

    f32x4 acc[8][4];
    #pragma unroll
    for (int i = 0; i < 8; ++i)
        #pragma unroll
        for (int j = 0; j < 4; ++j) {
            f32x4 z = {0.f, 0.f, 0.f, 0.f};
            acc[i][j] = z;
        }

    // stage-side state (wave-uniform), tracks the NEXT stage to issue
    int s_ci = 0, s_u = 0, s_v = 0, s_ky = 0, s_kx = 0;
    int s_ao, s_bo;
    if constexpr (MODE == 1) tap1(0, 0, s_ao, s_bo);
    else { s_ao = 0; s_bo = 0; }

    auto advance = [&]() {
        ++s_ci;
        s_ao += 32; s_bo += 16384;
        if (s_ci == 16) {
            s_ci = 0;
            if constexpr (MODE == 1) {
                if (++s_v == nkx) { s_v = 0; ++s_u; }
                tap1(s_u, s_v, s_ao, s_bo);
            } else {
                if (++s_kx == 3) { s_kx = 0; ++s_ky; }
                s_ao = (s_ky * 66 + s_kx) * 512;
                s_bo = (s_ky * 3 + s_kx) * 262144;
            }
        }
    };

    const int nstep = ntap * 16;   // always >= 16
    issue(0, s_ao, s_bo); advance();
    issue(1, s_ao, s_bo); advance();

    int sl = 0, slp = 2;           // slot of buf[it] / of stage(it+2)
    for (int it = 0; it < nstep; ++it) {
        if (it + 1 < nstep) asm volatile("s_waitcnt vmcnt(6)" ::: "memory");
        else                asm volatile("s_waitcnt vmcnt(0)" ::: "memory");
        __builtin_amdgcn_s_barrier();
        __builtin_amdgcn_sched_barrier(0);

        const ushort_t* __restrict__ curA = As[sl];
        const ushort_t* __restrict__ curB = Bs[sl];
        bf16x8 aF[8], bF[4];
        #pragma unroll
        for (int mi = 0; mi < 8; ++mi)
            aF[mi] = *(const bf16x8*)&curA[ra[mi]];
        #pragma unroll
        for (int ni = 0; ni < 4; ++ni)
            bF[ni] = *(const bf16x8*)&curB[rb[ni]];

        if (it + 2 < nstep) {
            issue(slp, s_ao, s_bo);
            advance();
        }

        __builtin_amdgcn_s_setprio(1);
        #pragma unroll
        for (int mi = 0; mi < 8; ++mi)
            #pragma unroll
            for (int ni = 0; ni < 4; ++ni)
                acc[mi][ni] = __builtin_amdgcn_mfma_f32_16x16x32_bf16(
                    aF[mi], bF[ni], acc[mi][ni], 0, 0, 0);
        __builtin_amdgcn_s_setprio(0);

        sl  = (sl == 2)  ? 0 : sl + 1;
        slp = (slp == 2) ? 0 : slp + 1;
    }

    // epilogue: D col = lane&15 (n), row = (lane>>4)*4 + reg (m)
    ushort_t* outb = (ushort_t*)out;   // MODE 1 writes bf16 t0
    #pragma unroll
    for (int ni = 0; ni < 4; ++ni) {
        const int n = n0 + wc * 64 + ni * 16 + ln15;
        const float gv = g[b * C + n];
        float snv = 0.f, bv = 0.f;
        if constexpr (MODE == 2) { snv = sn[n]; bv = bias[n]; }
        #pragma unroll
        for (int mi = 0; mi < 8; ++mi) {
            #pragma unroll
            for (int j = 0; j < 4; ++j) {
                const int m = wr * 128 + mi * 16 + lg * 4 + j;
                if constexpr (MODE == 1) {
                    const int oy = 2 * (i0 + (m >> 5)) + cla;
                    const int ox = 2 * (m & 31) + clc;
                    const size_t idx = ((size_t)((b * HO + oy) * WO + ox) << 9) + n;
                    outb[idx] = f2bu(acc[mi][ni][j] * gv);
                } else {
                    const int oy = oyb * 4 + (m >> 6);
                    const int ox = m & 63;
                    const size_t idx = ((size_t)((b * HO + oy) * WO + ox) << 9) + n;
                    float v = acc[mi][ni][j] * gv;
                    out[idx] = lrelu(v + snv * nzs[m] + bv);
                }
            }
        }
    }
}

// 4x4 FIR blur + noise + bias + lrelu + s2 fold; bf16 t0 in, bf16 x1b (haloed) out.
// Block = (128-ch slab, output row, batch). Stages 4 input rows x 64 px x 128 ch
// into padded LDS [4][68][128] (70 KB, 2 blocks/CU); all 16 taps read from LDS
// as bf16x8 (contiguous 1024B per wave -> conflict-free). Fully coalesced int4 IO.
__global__ __launch_bounds__(256) void blur_kernel(
    const ushort_t* __restrict__ t0b, const float* __restrict__ noise1,
    const float* __restrict__ sn1, const float* __restrict__ bias1,
    const float* __restrict__ s2, ushort_t* __restrict__ x1, int b0)
{
    const int cb = blockIdx.x;      // channel slab 0..3
    const int oy = blockIdx.y;      // 0..63
    const int bq = blockIdx.z;      // 0..7
    const int b  = b0 + bq;
    const int tid = threadIdx.x;
    const int c0 = cb * 128;

    __shared__ ushort_t sm[4][68][128];   // [row][px+1][ch]; px slots 0,65,66,67 = pads
    __shared__ float prm[3][128];

    if (tid < 128) {
        prm[0][tid] = sn1[c0 + tid];
        prm[1][tid] = bias1[c0 + tid];
        prm[2][tid] = s2[b * C + c0 + tid];
    }
    #pragma unroll
    for (int rr = 0; rr < 4; ++rr) {
        const int iy = oy + rr - 1;
        const bool valid = (unsigned)iy < (unsigned)HO;
        #pragma unroll
        for (int l = 0; l < 4; ++l) {
            const int unit = tid + l * 256;        // 0..1023
            const int px = unit >> 4, q = (unit & 15) * 8;
            int4 v{0, 0, 0, 0};
            if (valid)
                v = *(const int4*)&t0b[(((size_t)b * HO + iy) * WO + px) * 512 + c0 + q];
            *(int4*)&sm[rr][px + 1][q] = v;
        }
    }
    {   // zero the 4 px pads per row: 4 slots x 4 rows x 16 int4 = 256 units
        const int si = tid >> 6, rr = (tid >> 4) & 3, qq = (tid & 15) * 8;
        const int ps[4] = {0, 65, 66, 67};
        int4 z{0, 0, 0, 0};
        *(int4*)&sm[rr][ps[si]][qq] = z;
    }
    __syncthreads();

    const float F2[4] = {1.f, 3.f, 3.f, 1.f};
    #pragma unroll
    for (int l = 0; l < 4; ++l) {
        const int unit = tid + l * 256;
        const int px = unit >> 4, q = (unit & 15) * 8;
        float acc[8] = {0.f, 0.f, 0.f, 0.f, 0.f, 0.f, 0.f, 0.f};
        #pragma unroll
        for (int i = 0; i < 4; ++i)
            #pragma unroll
            for (int j = 0; j < 4; ++j) {
                const float wgt = F2[i] * F2[j];
                bf16x8 v = *(const bf16x8*)&sm[i][px + j][q];   // ix = px+j-1 -> slot px+j
                #pragma unroll
                for (int e = 0; e < 8; ++e)
                    acc[e] = fmaf(wgt, (float)v[e], acc[e]);
            }
        const float nz = noise1[(b * HO + oy) * WO + px];
        ushort_t ov[8];
        #pragma unroll
        for (int e = 0; e < 8; ++e) {
            const int c = q + e;
            float vv = lrelu(fmaf(prm[0][c], nz, acc[e] * 0.0625f) + prm[1][c]) * prm[2][c];
            ov[e] = f2bu(vv);
        }
        *(int4*)&x1[(((size_t)bq * 66 + oy + 1) * 66 + (px + 1)) * 512 + c0 + q] = *(const int4*)ov;
    }
}

// 1x1 conv (no demod) + bias + lrelu -> rgb. Coalesced: 16 px x 16 lanes per
// block, 256B contiguous segments per 16-lane group, shfl_xor width-16 reduce.
__global__ __launch_bounds__(256) void torgb2_kernel(
    const float* __restrict__ x2, const float* __restrict__ srgb,
    const float* __restrict__ wr, const float* __restrict__ biasr,
    float* __restrict__ rgb)
{
    const int b = blockIdx.y;
    const int tid = threadIdx.x;
    __shared__ float weff[C][3];
    const float scale = 0.044194173824159216f;  // 1/sqrt(512) conv wscale
    for (int ci = tid; ci < C; ci += 256) {
        float sc = scale * srgb[b * C + ci];
        weff[ci][0] = sc * wr[ci * 3 + 0];
        weff[ci][1] = sc * wr[ci * 3 + 1];
        weff[ci][2] = sc * wr[ci * 3 + 2];
    }
    __syncthreads();
    const int l16 = tid & 15;
    const int px  = blockIdx.x * 16 + (tid >> 4);
    const float* base = x2 + ((size_t)(b * 4096 + px) << 9);
    float a0 = 0.f, a1 = 0.f, a2 = 0.f;
    #pragma unroll
    for (int i = 0; i < 8; ++i) {
        const int c = i * 64 + l16 * 4;
        const float4 v = *(const float4*)&base[c];
        a0 = fmaf(v.x, weff[c][0], a0);     a1 = fmaf(v.x, weff[c][1], a1);     a2 = fmaf(v.x, weff[c][2], a2);
        a0 = fmaf(v.y, weff[c+1][0], a0);   a1 = fmaf(v.y, weff[c+1][1], a1);   a2 = fmaf(v.y, weff[c+1][2], a2);
        a0 = fmaf(v.z, weff[c+2][0], a0);   a1 = fmaf(v.z, weff[c+2][1], a1);   a2 = fmaf(v.z, weff[c+2][2], a2);
        a0 = fmaf(v.w, weff[c+3][0], a0);   a1 = fmaf(v.w, weff[c+3][1], a1);   a2 = fmaf(v.w, weff[c+3][2], a2);
    }
    #pragma unroll
    for (int off = 1; off < 16; off <<= 1) {
        a0 += __shfl_xor(a0, off, 16);
        a1 += __shfl_xor(a1, off, 16);
        a2 += __shfl_xor(a2, off, 16);
    }
    if (l16 < 3) {
        float v = l16 == 0 ? a0 : (l16 == 1 ? a1 : a2);
        rgb[(size_t)(b * 4096 + px) * 3 + l16] = lrelu(v + biasr[l16]);
    }
}

extern "C" void kernel_launch(void* const* d_in, const int* in_sizes, int n_in,
                              void* d_out, int out_size, void* d_ws, size_t ws_size,
                              hipStream_t stream)
{
    (void)in_sizes; (void)n_in; (void)out_size; (void)ws_size;
    const float* x       = (const float*)d_in[0];
    const float* w       = (const float*)d_in[1];
    const float* noise1  = (const float*)d_in[2];
    const float* noise2  = (const float*)d_in[3];
    const float* fcl1_w  = (const float*)d_in[4];
    const float* fcl1_b  = (const float*)d_in[5];
    const float* conv1_w = (const float*)d_in[6];
    const float* sn1     = (const float*)d_in[7];
    const float* bias1   = (const float*)d_in[8];
    const float* fcl2_w  = (const float*)d_in[9];
    const float* fcl2_b  = (const float*)d_in[10];
    const float* conv2_w = (const float*)d_in[11];
    const float* sn2     = (const float*)d_in[12];
    const float* bias2   = (const float*)d_in[13];
    const float* fclr_w  = (const float*)d_in[14];
    const float* fclr_b  = (const float*)d_in[15];
    const float* convr_w = (const float*)d_in[16];
    const float* biasr   = (const float*)d_in[17];

    float* out_x2  = (float*)d_out;               // 16*64*64*512 fp32 = 128 MiB
    float* out_rgb = out_x2 + 33554432;           // 16*64*64*3 fp32 = 768 KiB (pure output)

    // bf16 t0 occupies EXACTLY the second half of out_x2 (bytes [64Mi,128Mi)).
    // Liveness: conv1 writes t0b (all 16 b); blur-half0 reads t0b[0:8]; conv2-half0
    // writes x2 bytes [0,64Mi) (no overlap with t0b); blur-half1 reads t0b[8:16]
    // (bytes [97.5Mi,128Mi)); conv2-half1 then overwrites [64Mi,128Mi). Safe.
    ushort_t* t0b = (ushort_t*)(out_x2 + 16777216);

    // d_ws layout (~62.2 MiB of the guaranteed 64):
    //   wb1  [0,       4.5Mi)  prepped conv1 weights
    //   wb2  [4.5Mi,   9.0Mi)  prepped conv2 weights
    //   xsp  [9.0Mi,  26.0Mi)  bf16 x*s1 haloed [16][33][33][512]
    //   x1b  [26.0Mi, 60.05Mi) bf16 x1*s2 haloed [8][66][66][512], half-batch ping
    //   scr  [60.05Mi, ...]    s1,s2,g1,g2,srgb (8K floats each) + q1,q2 (256K each)
    ushort_t* wb1 = (ushort_t*)d_ws;
    ushort_t* wb2 = wb1 + 2359296;                   // 9*16*512*32
    ushort_t* xsp = wb1 + 4718592;
    ushort_t* x1b = xsp + 8921088;                   // 16*33*33*512
    float* scr = (float*)(x1b + 17842176);           // 8*66*66*512
    float* s1   = scr;
    float* s2   = scr + 8192;
    float* g1   = scr + 16384;
    float* g2   = scr + 24576;
    float* srgb = scr + 32768;
    float* q1   = scr + 40960;
    float* q2   = scr + 303104;

    const float WS33 = 0.014731391274719739f;     // 1/sqrt(9*512)

    style3_kernel<<<dim3(NB, 3), 256, 0, stream>>>(
        w, fcl1_w, fcl1_b, fcl2_w, fcl2_b, fclr_w, fclr_b, s1, s2, srgb);
    wprep2_kernel<<<dim3(8, 16, 2), 256, 0, stream>>>(conv1_w, conv2_w, wb1, wb2, q1, q2);
    demod3_kernel<<<dim3(2, NB, 2), 256, 0, stream>>>(s1, s2, q1, q2, g1, g2, WS33);
    xprep_kernel<<<8712, 256, 0, stream>>>(x, s1, xsp);
    zero_halo_kernel<<<520, 256, 0, stream>>>(x1b);

    conv_mfma<1><<<dim3(4, 16, NB), 256, 0, stream>>>(
        xsp, wb1, g1, nullptr, nullptr, nullptr, (float*)t0b, 0);

    for (int half = 0; half < 2; ++half) {
        // blur(half) consumes t0b[b in half] before conv2(half) overwrites that region
        blur_kernel<<<dim3(4, HO, 8), 256, 0, stream>>>(
            t0b, noise1, sn1, bias1, s2, x1b, half * 8);
        conv_mfma<2><<<dim3(4, 16, 8), 256, 0, stream>>>(
            x1b, wb2, g2, noise2, sn2, bias2, out_x2, half * 8);
    }

    torgb2_kernel<<<dim3(256, NB), 256, 0, stream>>>(out_x2, srgb, convr_w, biasr, out_rgb);
}